// Round 9
// baseline (423.658 us; speedup 1.0000x reference)
//
#include <hip/hip_runtime.h>

// PureWaveAttention B=2,T=2048,D=1024,H=16,NW=64,HD=64 — fp32 I/O, all GEMMs
// on MFMA via 2-term fp16 split: a = hi + lo/2048 (lo stored pre-scaled x2048).
// C = hh(hi,hi) + mx(hi,lo + lo,hi)/2048. Rel err 2^-22 -> fp32-equivalent.
// Pipeline:
//  0) xsplit: x fp32 -> xhi/xlo fp16 (aliases G region, dead until chunk_kv)
//  0b) wsplit: W{qf,qp,kf,kp,v,o} fp32[k][n] -> Whi/Wlo fp16[n][k]
//  1) proj: qn/kn = normalize(sin((x@Wf+bf)*t + (x@Wp+bp))) -> fp16
//  2) vgemm: v = x@Wv+bv -> fp32 in d_out (consumed before out-gemm)
//  3) chunk_kv -> G; prefix -> M; attn_chunk -> att split fp16 (aliases qnh/knh)
//  4) outgemm: d_out = att@Wo+bo
// R9: proj M=64/WAVE. Five scheduling variants all pinned proj at 136-148us,
// MfmaUtil 33% — matches LDS-BW model exactly: all 4 waves re-read the same
// 16KB B tile per phase (B frags are lane-indexed, wave-invariant) -> per-CU
// LDS 8x16KB=1024cyc vs MFMA 384cyc. Fix: wave covers 64 rows (2 row-groups),
// reusing each B fragment across 2x MFMAs. Block=256 rows, acc 256 VGPR,
// 1 wave/SIMD (launch_bounds(256,1)); latency covered by R8 quad-buffer
// (stage 2 phases ahead, vmcnt(4) barriers). Predicted util ceiling ~75%.
// gemm: R7 BAR_LG version (best measured; R5 warns against geometry changes).
// ws (56 MB): Wsplit 24 | qnh 8 | knh 8 | G 16 (xhi/xlo alias G before chunk_kv)

#define Bb 2
#define Tt 2048
#define Dd 1024
#define Hh 16
#define NC 32

typedef _Float16 half_t;
typedef _Float16 half8 __attribute__((ext_vector_type(8)));
typedef _Float16 half4h __attribute__((ext_vector_type(4)));
typedef float f32x16 __attribute__((ext_vector_type(16)));

#define MFMA32(a, b, c) __builtin_amdgcn_mfma_f32_32x32x16_f16((a), (b), (c), 0, 0, 0)

// global_load_lds: per-lane global src, wave-uniform LDS base + lane*16.
#define GLL(G, L) __builtin_amdgcn_global_load_lds(                      \
    (const __attribute__((address_space(1))) void*)(G),                  \
    (__attribute__((address_space(3))) void*)(L), 16, 0, 0)

#define SCHED_FENCE() __builtin_amdgcn_sched_barrier(0)

// proj phase barrier: drain all but the 4 newest vmem ops (= this phase's
// GLLs). No sched fences (R7 lesson).
#define BARC() {                                                         \
    asm volatile("s_waitcnt vmcnt(4) lgkmcnt(0)" ::: "memory");          \
    __builtin_amdgcn_s_barrier(); }

// gemm phase barrier, LDS ordering only (vmem stays in flight) — R7 version.
#define BAR_LG() {                                                       \
    SCHED_FENCE();                                                       \
    asm volatile("s_waitcnt lgkmcnt(0)" ::: "memory");                   \
    __builtin_amdgcn_s_barrier();                                        \
    SCHED_FENCE(); }

// ---------------------------------------------------------------------------
// Kernel -1: split x fp32 -> xhi, xlo fp16 (lo pre-scaled x2048).
// ---------------------------------------------------------------------------
__global__ __launch_bounds__(256) void xsplit_kernel(
    const float* __restrict__ X, half_t* __restrict__ XHI, half_t* __restrict__ XLO)
{
  const size_t i = ((size_t)blockIdx.x * 256 + threadIdx.x) * 8;
  float4 a = *(const float4*)&X[i];
  float4 b = *(const float4*)&X[i + 4];
  const float av[8] = {a.x, a.y, a.z, a.w, b.x, b.y, b.z, b.w};
  half8 hv, lv;
  #pragma unroll
  for (int j = 0; j < 8; ++j) {
    half_t hx = (half_t)av[j];
    hv[j] = hx; lv[j] = (half_t)((av[j] - (float)hx) * 2048.f);
  }
  *(half8*)&XHI[i] = hv;
  *(half8*)&XLO[i] = lv;
}

// ---------------------------------------------------------------------------
// Kernel 0: split+transpose weights: W[k][n] fp32 -> hi[n][k], lo[n][k] fp16.
// Per matrix: hi at m*2097152 halves, lo at +1048576.
// ---------------------------------------------------------------------------
__global__ __launch_bounds__(256) void wsplit_kernel(
    const float* __restrict__ W0, const float* __restrict__ W1,
    const float* __restrict__ W2, const float* __restrict__ W3,
    const float* __restrict__ W4, const float* __restrict__ W5,
    half_t* __restrict__ WSP)
{
  __shared__ float Ld[64][68];
  const int tid = threadIdx.x;
  const int m = blockIdx.z;
  const float* W = (m == 0) ? W0 : (m == 1) ? W1 : (m == 2) ? W2
                 : (m == 3) ? W3 : (m == 4) ? W4 : W5;
  const int k0 = blockIdx.x * 64, n0 = blockIdx.y * 64;
  const int r = tid >> 2, c4 = (tid & 3) * 16;
  #pragma unroll
  for (int i = 0; i < 4; ++i)
    *(float4*)&Ld[r][c4 + i * 4] =
        *(const float4*)&W[(size_t)(k0 + r) * Dd + n0 + c4 + i * 4];
  __syncthreads();
  half_t* hi = WSP + (size_t)m * 2097152;
  half_t* lo = hi + 1048576;
  const int n = tid >> 2, kc = (tid & 3) * 16;
  half8 hv0, hv1, lv0, lv1;
  #pragma unroll
  for (int i = 0; i < 8; ++i) {
    float v0 = Ld[kc + i][n];
    half_t h0 = (half_t)v0;
    hv0[i] = h0; lv0[i] = (half_t)((v0 - (float)h0) * 2048.f);
    float v1 = Ld[kc + 8 + i][n];
    half_t h1 = (half_t)v1;
    hv1[i] = h1; lv1[i] = (half_t)((v1 - (float)h1) * 2048.f);
  }
  *(half8*)&hi[(size_t)(n0 + n) * Dd + k0 + kc]     = hv0;
  *(half8*)&hi[(size_t)(n0 + n) * Dd + k0 + kc + 8] = hv1;
  *(half8*)&lo[(size_t)(n0 + n) * Dd + k0 + kc]     = lv0;
  *(half8*)&lo[(size_t)(n0 + n) * Dd + k0 + kc + 8] = lv1;
}

// ---------------------------------------------------------------------------
// Kernel 1: proj. Block = 256 t-rows x (64 F | 64 P) cols for head h, pair p.
// Wave w: rows 64w..64w+63 (TWO 32-row groups, A in registers), all 128 B
// cols -> 8 32x32 acc tiles (2 groups x {F0,F1,P0,P1}) x (hh,mx).
// B QUAD-buffered in LDS via global_load_lds (stage 2 phases ahead).
// Phase: {LOADA8 A(p+1) | STAGE GLL buf(p+2) | 48 MFMA | BARC vmcnt(4)}.
// Each B fragment read feeds 2 row-groups -> per-CU LDS traffic halved vs R8.
// B LDS tile: [128 rows][64 halves]; row = 8x16B chunks [hi oct0..3|lo 0..3],
// chunk c at phys c^(row&7); per-lane GLOBAL source pre-swizzled to match.
// ---------------------------------------------------------------------------
__global__ __launch_bounds__(256, 1) void proj_kernel(
    const half_t* __restrict__ XHI, const half_t* __restrict__ XLO,
    const half_t* __restrict__ WSP,
    const float* __restrict__ bqf, const float* __restrict__ bqp,
    const float* __restrict__ bkf, const float* __restrict__ bkp,
    half_t* __restrict__ QNH, half_t* __restrict__ KNH)
{
  __shared__ __align__(16) half_t Bs[4][128][64];
  const int tid = threadIdx.x;
  const int mb = blockIdx.x, h = blockIdx.y;
  const int b = blockIdx.z >> 1, p = blockIdx.z & 1;
  const int t0 = mb * 256, row0 = b * Tt + t0, col0 = h * 64;
  const half_t* WF = WSP + (size_t)(2 * p) * 2097152;      // hi; lo at +1048576
  const half_t* WP = WSP + (size_t)(2 * p + 1) * 2097152;
  const float* BF = p ? bkf : bqf;
  const float* BP = p ? bkp : bqp;
  half_t* OUTH = p ? KNH : QNH;

  f32x16 hh0[4], mx0[4], hh1[4], mx1[4];
  #pragma unroll
  for (int i = 0; i < 4; ++i) {
    hh0[i] = (f32x16)(0.f); mx0[i] = (f32x16)(0.f);
    hh1[i] = (f32x16)(0.f); mx1[i] = (f32x16)(0.f);
  }

  const int lane = tid & 63, w = tid >> 6;
  const int rl = lane & 31, kq = lane >> 5;
  const int sw = rl & 7;

  // A (x) sources: group0 row 64w+rl, group1 row 64w+32+rl; k-octets kq, 2+kq.
  const half_t* aHi0 = XHI + (size_t)(row0 + 64 * w + rl) * Dd + kq * 8;
  const half_t* aLo0 = XLO + (size_t)(row0 + 64 * w + rl) * Dd + kq * 8;
  const half_t* aHi1 = aHi0 + 32 * Dd;
  const half_t* aLo1 = aLo0 + 32 * Dd;

  // B staging sources (per-lane, inverse-swizzled chunk):
  const int lr8 = lane >> 3;                 // row-within-8
  const int lcc = (lane & 7) ^ lr8;          // logical chunk this lane fetches
  const int csel = (lcc & 3) * 8;            // k sub-offset (halves)
  const size_t loOff = (lcc >= 4) ? 1048576 : 0;
  const half_t* gb0 = WF + loOff + (size_t)(col0 + 8 * w + lr8) * Dd + csel;
  const half_t* gb1 = gb0 + 32 * Dd;
  const half_t* gb2 = WP + loOff + (size_t)(col0 + 8 * w + lr8) * Dd + csel;
  const half_t* gb3 = gb2 + 32 * Dd;

#define STAGE_PB(BI, K) {                          \
    GLL(gb0 + (K), &Bs[BI][8 * w][0]);             \
    GLL(gb1 + (K), &Bs[BI][32 + 8 * w][0]);        \
    GLL(gb2 + (K), &Bs[BI][64 + 8 * w][0]);        \
    GLL(gb3 + (K), &Bs[BI][96 + 8 * w][0]); }

// load both row-groups' A fragments for k-tile K into an 8-reg set
#define LOADA8(R00, R01, R02, R03, R10, R11, R12, R13, K) {  \
    R00 = *(const half8*)&aHi0[(K)];                         \
    R01 = *(const half8*)&aHi0[(K) + 16];                    \
    R02 = *(const half8*)&aLo0[(K)];                         \
    R03 = *(const half8*)&aLo0[(K) + 16];                    \
    R10 = *(const half8*)&aHi1[(K)];                         \
    R11 = *(const half8*)&aHi1[(K) + 16];                    \
    R12 = *(const half8*)&aLo1[(K)];                         \
    R13 = *(const half8*)&aLo1[(K) + 16]; }

// one 32-k tile of MFMAs from buffer BI; each bh/bl feeds both row-groups
#define KT2(R00, R01, R02, R03, R10, R11, R12, R13, BI) {              \
    { const int c0 = (kq ^ sw) * 8, c1 = ((4 + kq) ^ sw) * 8;          \
      _Pragma("unroll")                                                \
      for (int tn = 0; tn < 4; ++tn) {                                 \
        half8 bh = *(const half8*)&Bs[BI][32 * tn + rl][c0];           \
        half8 bl = *(const half8*)&Bs[BI][32 * tn + rl][c1];           \
        hh0[tn] = MFMA32(R00, bh, hh0[tn]);                            \
        mx0[tn] = MFMA32(R00, bl, mx0[tn]);                            \
        mx0[tn] = MFMA32(R02, bh, mx0[tn]);                            \
        hh1[tn] = MFMA32(R10, bh, hh1[tn]);                            \
        mx1[tn] = MFMA32(R10, bl, mx1[tn]);                            \
        mx1[tn] = MFMA32(R12, bh, mx1[tn]); } }                        \
    { const int c0 = ((2 + kq) ^ sw) * 8, c1 = ((6 + kq) ^ sw) * 8;    \
      _Pragma("unroll")                                                \
      for (int tn = 0; tn < 4; ++tn) {                                 \
        half8 bh = *(const half8*)&Bs[BI][32 * tn + rl][c0];           \
        half8 bl = *(const half8*)&Bs[BI][32 * tn + rl][c1];           \
        hh0[tn] = MFMA32(R01, bh, hh0[tn]);                            \
        mx0[tn] = MFMA32(R01, bl, mx0[tn]);                            \
        mx0[tn] = MFMA32(R03, bh, mx0[tn]);                            \
        hh1[tn] = MFMA32(R11, bh, hh1[tn]);                            \
        mx1[tn] = MFMA32(R11, bl, mx1[tn]);                            \
        mx1[tn] = MFMA32(R13, bh, mx1[tn]); } } }

  half8 c00, c01, c02, c03, c10, c11, c12, c13;
  half8 n00, n01, n02, n03, n10, n11, n12, n13;
  // prologue: stage buf0,buf1; load A(k=0).
  STAGE_PB(0, 0)
  STAGE_PB(1, 32)
  LOADA8(c00, c01, c02, c03, c10, c11, c12, c13, 0)
  BARC()

  #pragma unroll 1
  for (int k0 = 0; k0 < Dd; k0 += 128) {      // 4 phases (32-k each) per iter
    // phase a: compute buf0 (k0); A(k0+32); stage buf2 (k0+64)
    LOADA8(n00, n01, n02, n03, n10, n11, n12, n13, k0 + 32)
    STAGE_PB(2, k0 + 64)
    KT2(c00, c01, c02, c03, c10, c11, c12, c13, 0)
    BARC()
    // phase b: compute buf1 (k0+32); A(k0+64); stage buf3 (k0+96)
    LOADA8(c00, c01, c02, c03, c10, c11, c12, c13, k0 + 64)
    STAGE_PB(3, k0 + 96)
    KT2(n00, n01, n02, n03, n10, n11, n12, n13, 1)
    BARC()
    // phase c: compute buf2 (k0+64); A(k0+96); stage buf0 (k0+128)
    LOADA8(n00, n01, n02, n03, n10, n11, n12, n13, k0 + 96)
    if (k0 + 128 < Dd) { STAGE_PB(0, k0 + 128) }
    KT2(c00, c01, c02, c03, c10, c11, c12, c13, 2)
    BARC()
    // phase d: compute buf3 (k0+96); A(k0+128); stage buf1 (k0+160)
    if (k0 + 128 < Dd) { LOADA8(c00, c01, c02, c03, c10, c11, c12, c13, k0 + 128) }
    if (k0 + 160 < Dd) { STAGE_PB(1, k0 + 160) }
    KT2(n00, n01, n02, n03, n10, n11, n12, n13, 3)
    BARC()
  }
#undef STAGE_PB
#undef LOADA8
#undef KT2

  const float bf0 = BF[col0 + rl], bf1 = BF[col0 + 32 + rl];
  const float bp0 = BP[col0 + rl], bp1 = BP[col0 + 32 + rl];
  #pragma unroll
  for (int g = 0; g < 2; ++g) {
    #pragma unroll
    for (int j = 0; j < 16; ++j) {
      const int rtj = (j & 3) + 8 * (j >> 2) + 4 * kq;  // row within 32-tile
      const int trow = t0 + 64 * w + 32 * g + rtj;
      const float tf = (float)trow;
      float f0 = (g ? hh1[0][j] : hh0[0][j]) + (g ? mx1[0][j] : mx0[0][j]) * (1.f / 2048.f) + bf0;
      float f1 = (g ? hh1[1][j] : hh0[1][j]) + (g ? mx1[1][j] : mx0[1][j]) * (1.f / 2048.f) + bf1;
      float p0 = (g ? hh1[2][j] : hh0[2][j]) + (g ? mx1[2][j] : mx0[2][j]) * (1.f / 2048.f) + bp0;
      float p1 = (g ? hh1[3][j] : hh0[3][j]) + (g ? mx1[3][j] : mx0[3][j]) * (1.f / 2048.f) + bp1;
      float w0 = sinf(fmaf(f0, tf, p0));
      float w1 = sinf(fmaf(f1, tf, p1));
      float ss = w0 * w0 + w1 * w1;
      ss += __shfl_xor(ss, 1); ss += __shfl_xor(ss, 2);
      ss += __shfl_xor(ss, 4); ss += __shfl_xor(ss, 8);
      ss += __shfl_xor(ss, 16);
      const float inv = 1.f / fmaxf(sqrtf(ss), 1e-12f);
      half_t* op = &OUTH[((size_t)(b * Tt) + trow) * Dd + col0];
      op[rl]      = (half_t)(w0 * inv);
      op[32 + rl] = (half_t)(w1 * inv);
    }
  }
}

// ---------------------------------------------------------------------------
// Kernel 2/4: GEMM OUT[4096,1024] = A@W + bias. R2 structure (128x128 dbuf,
// row-per-thread ds_write staging, XOR-swz) with lgkm-only barriers: the 8
// global prefetch loads stay in flight across phase boundaries. (R7, kept.)
// ---------------------------------------------------------------------------
__global__ __launch_bounds__(256, 2) void gemm_kernel(
    const half_t* __restrict__ AHI, const half_t* __restrict__ ALO,
    const half_t* __restrict__ WHI,
    const float* __restrict__ BIAS, float* __restrict__ OUT)
{
  __shared__ __align__(16) half_t As[2][128][64];
  __shared__ __align__(16) half_t Bs[2][128][64];
  const int tid = threadIdx.x;
  const int m0 = blockIdx.x * 128, n0 = blockIdx.y * 128;

  f32x16 hh[4], mx[4];
  #pragma unroll
  for (int i = 0; i < 4; ++i) { hh[i] = (f32x16)(0.f); mx[i] = (f32x16)(0.f); }

  const int lane = tid & 63, w = tid >> 6;
  const int rl = lane & 31, kq = lane >> 5;
  const int sw = rl & 7;

  const int r = tid & 127, isB = tid >> 7;
  const int swr = r & 7;
  const half_t* srcHi = isB ? &WHI[(size_t)(n0 + r) * Dd]
                            : &AHI[(size_t)(m0 + r) * Dd];
  const half_t* srcLo = isB ? &WHI[1048576 + (size_t)(n0 + r) * Dd]
                            : &ALO[(size_t)(m0 + r) * Dd];
  half_t* dstRow = isB ? &Bs[0][r][0] : &As[0][r][0];
  const int pc0 = (0 ^ swr) * 8, pc1 = (1 ^ swr) * 8;
  const int pc2 = (2 ^ swr) * 8, pc3 = (3 ^ swr) * 8;
  const int pc4 = (4 ^ swr) * 8, pc5 = (5 ^ swr) * 8;
  const int pc6 = (6 ^ swr) * 8, pc7 = (7 ^ swr) * 8;

  half8 rg0, rg1, rg2, rg3, rg4, rg5, rg6, rg7;

#define G_LOADREGS(K)                                                          \
  rg0 = *(const half8*)&srcHi[(K)];      rg1 = *(const half8*)&srcHi[(K) + 8]; \
  rg2 = *(const half8*)&srcHi[(K) + 16]; rg3 = *(const half8*)&srcHi[(K) + 24];\
  rg4 = *(const half8*)&srcLo[(K)];      rg5 = *(const half8*)&srcLo[(K) + 8]; \
  rg6 = *(const half8*)&srcLo[(K) + 16]; rg7 = *(const half8*)&srcLo[(K) + 24];

#define G_WRITE(BI) {                                                     \
  half_t* d_ = dstRow + (BI) * 8192;                                      \
  *(half8*)&d_[pc0] = rg0; *(half8*)&d_[pc1] = rg1;                       \
  *(half8*)&d_[pc2] = rg2; *(half8*)&d_[pc3] = rg3;                       \
  *(half8*)&d_[pc4] = rg4; *(half8*)&d_[pc5] = rg5;                       \
  *(half8*)&d_[pc6] = rg6; *(half8*)&d_[pc7] = rg7; }

#define G_KT(BI)                                                          \
  _Pragma("unroll")                                                       \
  for (int ks = 0; ks < 2; ++ks) {                                        \
    half8 ahi = *(const half8*)&As[BI][32 * w + rl][((2 * ks + kq) ^ sw) * 8];       \
    half8 alo = *(const half8*)&As[BI][32 * w + rl][((4 + 2 * ks + kq) ^ sw) * 8];   \
    _Pragma("unroll")                                                     \
    for (int tn = 0; tn < 4; ++tn) {                                      \
      half8 bhi = *(const half8*)&Bs[BI][32 * tn + rl][((2 * ks + kq) ^ sw) * 8];    \
      half8 blo = *(const half8*)&Bs[BI][32 * tn + rl][((4 + 2 * ks + kq) ^ sw) * 8];\
      hh[tn] = MFMA32(ahi, bhi, hh[tn]);                                  \
      mx[tn] = MFMA32(ahi, blo, mx[tn]);                                  \
      mx[tn] = MFMA32(alo, bhi, mx[tn]);                                  \
    }                                                                     \
  }

  G_LOADREGS(0)
  G_WRITE(0)
  G_LOADREGS(32)
  BAR_LG()

  #pragma unroll 1
  for (int k0 = 0; k0 < Dd; k0 += 64) {
    G_KT(0)
    G_WRITE(1)
    if (k0 + 64 < Dd) { G_LOADREGS(k0 + 64) }
    BAR_LG()
    G_KT(1)
    if (k0 + 64 < Dd) { G_WRITE(0) }
    if (k0 + 96 < Dd) { G_LOADREGS(k0 + 96) }
    BAR_LG()
  }
#undef G_LOADREGS
#undef G_WRITE
#undef G_KT

  const float bb0 = BIAS[n0 + rl],      bb1 = BIAS[n0 + 32 + rl];
  const float bb2 = BIAS[n0 + 64 + rl], bb3 = BIAS[n0 + 96 + rl];
  #pragma unroll
  for (int j = 0; j < 16; ++j) {
    const int rtj = (j & 3) + 8 * (j >> 2) + 4 * kq;
    float* orow = &OUT[(size_t)(m0 + 32 * w + rtj) * Dd + n0];
    orow[rl]      = hh[0][j] + mx[0][j] * (1.f / 2048.f) + bb0;
    orow[32 + rl] = hh[1][j] + mx[1][j] * (1.f / 2048.f) + bb1;
    orow[64 + rl] = hh[2][j] + mx[2][j] * (1.f / 2048.f) + bb2;
    orow[96 + rl] = hh[3][j] + mx[3][j] * (1.f / 2048.f) + bb3;
  }
}

// ---------------------------------------------------------------------------
// Kernel 3a: G_c[w][d] = sum_{s in c} K[s][w]*V[s][d]. K from fp16, V fp32.
// ---------------------------------------------------------------------------
__global__ __launch_bounds__(256) void chunk_kv_kernel(
    const half_t* __restrict__ KNH, const float* __restrict__ V,
    float* __restrict__ G)
{
  __shared__ float Ks[64][64];
  __shared__ float Vs[64][64];
  const int tid = threadIdx.x;
  const int c = blockIdx.x, h = blockIdx.y, b = blockIdx.z;
  const int s0 = c * 64;
  const int lr = tid >> 2, lc = (tid & 3) * 16;
  {
    const half_t* krow = &KNH[(size_t)(b * Tt + s0 + lr) * Dd + h * 64 + lc];
    half8 ka = *(const half8*)&krow[0];
    half8 kb = *(const half8*)&krow[8];
    #pragma unroll
    for (int i = 0; i < 8; ++i) {
      Ks[lr][lc + i] = (float)ka[i];
      Ks[lr][lc + 8 + i] = (float)kb[i];
    }
    const float* vrow = &V[(size_t)(b * Tt + s0 + lr) * Dd + h * 64 + lc];
    #pragma unroll
    for (int i = 0; i < 4; ++i)
      *(float4*)&Vs[lr][lc + i * 4] = *(const float4*)&vrow[i * 4];
  }
  __syncthreads();

  const int ty = tid >> 4, tx = tid & 15;
  float g[4][4] = {{0.f}};
  #pragma unroll 4
  for (int s = 0; s < 64; ++s) {
    float4 kv = *(const float4*)&Ks[s][ty * 4];
    float4 vv = *(const float4*)&Vs[s][tx * 4];
    const float* k_ = (const float*)&kv;
    const float* v_ = (const float*)&vv;
    #pragma unroll
    for (int i = 0; i < 4; ++i)
      #pragma unroll
      for (int j = 0; j < 4; ++j)
        g[i][j] = fmaf(k_[i], v_[j], g[i][j]);
  }
  float* Gp = G + (((size_t)(b * Hh + h) * NC + c) << 12);
  #pragma unroll
  for (int i = 0; i < 4; ++i)
    *(float4*)&Gp[(ty * 4 + i) * 64 + tx * 4] =
        make_float4(g[i][0], g[i][1], g[i][2], g[i][3]);
}

// ---------------------------------------------------------------------------
// Kernel 3b: in-place exclusive prefix over NC chunk matrices per (b,h).
// 512 blocks; thread = 1 float, fully coalesced.
// ---------------------------------------------------------------------------
__global__ __launch_bounds__(256) void prefix_kernel(float* __restrict__ G)
{
  const int seg = blockIdx.x, h = blockIdx.y, b = blockIdx.z;
  float* base = G + (((size_t)(b * Hh + h) * NC) << 12) + seg * 256 + threadIdx.x;
  float acc = 0.f;
  #pragma unroll 4
  for (int c = 0; c < NC; ++c) {
    float* p = base + ((size_t)c << 12);
    const float g = *p;
    *p = acc;
    acc += g;
  }
}

// ---------------------------------------------------------------------------
// Kernel 3c: O_c = (Q_c M_c + tril(Q_c K_c^T) V_c) * scale/sqrt(t+1).
// Q,K from fp16; out split to fp16 hi/lo (lo x2048), aliasing qnh/knh.
// ---------------------------------------------------------------------------
__global__ __launch_bounds__(256) void attn_chunk_kernel(
    const half_t* __restrict__ QNH, const half_t* __restrict__ KNH,
    const float* __restrict__ V, const float* __restrict__ M,
    const float* __restrict__ SCALE,
    half_t* __restrict__ ATTHI, half_t* __restrict__ ATTLO)
{
  __shared__ float Qt[64][68];
  __shared__ float Kt[64][68];
  __shared__ float SM[64][68];
  __shared__ float Vs[64][64];
  const int tid = threadIdx.x;
  const int c = blockIdx.x, h = blockIdx.y, b = blockIdx.z;
  const int t0 = c * 64;
  const int lr = tid >> 2, lc = (tid & 3) * 16;
  {
    const half_t* qrow = &QNH[(size_t)(b * Tt + t0 + lr) * Dd + h * 64 + lc];
    const half_t* krow = &KNH[(size_t)(b * Tt + t0 + lr) * Dd + h * 64 + lc];
    half8 qa = *(const half8*)&qrow[0];
    half8 qb = *(const half8*)&qrow[8];
    half8 ka = *(const half8*)&krow[0];
    half8 kb = *(const half8*)&krow[8];
    #pragma unroll
    for (int i = 0; i < 8; ++i) {
      Qt[lc + i][lr] = (float)qa[i];     Qt[lc + 8 + i][lr] = (float)qb[i];
      Kt[lc + i][lr] = (float)ka[i];     Kt[lc + 8 + i][lr] = (float)kb[i];
    }
    const float* vrow = &V[(size_t)(b * Tt + t0 + lr) * Dd + h * 64 + lc];
    const float* mrow = &M[(((size_t)(b * Hh + h) * NC + c) << 12) + lr * 64 + lc];
    #pragma unroll
    for (int i = 0; i < 4; ++i) {
      *(float4*)&Vs[lr][lc + i * 4] = *(const float4*)&vrow[i * 4];
      *(float4*)&SM[lr][lc + i * 4] = *(const float4*)&mrow[i * 4];
    }
  }
  __syncthreads();

  const int ty = tid >> 4, tx = tid & 15;
  float o[4][4] = {{0.f}};
  float sc[4][4] = {{0.f}};

  #pragma unroll 4
  for (int w = 0; w < 64; ++w) {
    float4 qv = *(const float4*)&Qt[w][ty * 4];
    float4 mv = *(const float4*)&SM[w][tx * 4];
    float4 kv = *(const float4*)&Kt[w][tx * 4];
    const float* q_ = (const float*)&qv;
    const float* m_ = (const float*)&mv;
    const float* k_ = (const float*)&kv;
    #pragma unroll
    for (int i = 0; i < 4; ++i) {
      float qq = q_[i];
      #pragma unroll
      for (int j = 0; j < 4; ++j) {
        o[i][j]  = fmaf(qq, m_[j], o[i][j]);
        sc[i][j] = fmaf(qq, k_[j], sc[i][j]);
      }
    }
  }
  __syncthreads();

  #pragma unroll
  for (int i = 0; i < 4; ++i) {
    const int lt = ty * 4 + i;
    #pragma unroll
    for (int j = 0; j < 4; ++j) {
      const int ls = tx * 4 + j;
      SM[ls][lt] = (ls <= lt) ? sc[i][j] : 0.f;
    }
  }
  __syncthreads();

  #pragma unroll 4
  for (int s = 0; s < 64; ++s) {
    float4 sv = *(const float4*)&SM[s][ty * 4];
    float4 vv = *(const float4*)&Vs[s][tx * 4];
    const float* s_ = (const float*)&sv;
    const float* v_ = (const float*)&vv;
    #pragma unroll
    for (int i = 0; i < 4; ++i)
      #pragma unroll
      for (int j = 0; j < 4; ++j)
        o[i][j] = fmaf(s_[i], v_[j], o[i][j]);
  }

  const float sch = SCALE[h];
  #pragma unroll
  for (int i = 0; i < 4; ++i) {
    const int t = t0 + ty * 4 + i;
    const float fac = sch / sqrtf((float)(t + 1));
    half4h hv, lv;
    #pragma unroll
    for (int j = 0; j < 4; ++j) {
      float v = o[i][j] * fac;
      half_t hx = (half_t)v;
      hv[j] = hx; lv[j] = (half_t)((v - (float)hx) * 2048.f);
    }
    *(half4h*)&ATTHI[(size_t)(b * Tt + t) * Dd + h * 64 + tx * 4] = hv;
    *(half4h*)&ATTLO[(size_t)(b * Tt + t) * Dd + h * 64 + tx * 4] = lv;
  }
}

// ---------------------------------------------------------------------------
extern "C" void kernel_launch(void* const* d_in, const int* in_sizes, int n_in,
                              void* d_out, int out_size, void* d_ws, size_t ws_size,
                              hipStream_t stream) {
  const float* x   = (const float*)d_in[0];
  const float* Wqf = (const float*)d_in[1];
  const float* bqf = (const float*)d_in[2];
  const float* Wkf = (const float*)d_in[3];
  const float* bkf = (const float*)d_in[4];
  const float* Wqp = (const float*)d_in[5];
  const float* bqp = (const float*)d_in[6];
  const float* Wkp = (const float*)d_in[7];
  const float* bkp = (const float*)d_in[8];
  const float* Wv  = (const float*)d_in[9];
  const float* bv  = (const float*)d_in[10];
  const float* Wo  = (const float*)d_in[11];
  const float* bo  = (const float*)d_in[12];
  const float* scale = (const float*)d_in[13];

  // ws layout (56 MB): Wsplit 24 MB | qnh 8 MB | knh 8 MB | G 16 MB
  half_t* WSP = (half_t*)d_ws;                 // 6 mats x (hi 1M + lo 1M) halves
  half_t* qnh = WSP + 12582912;                // 4,194,304 halves
  half_t* knh = qnh + 4194304;
  float*  G   = (float*)(knh + 4194304);
  half_t* xhi = (half_t*)G;                    // x halves alias G: dead before
  half_t* xlo = xhi + 4194304;                 // chunk_kv writes G
  float*  vbuf = (float*)d_out;                // v lives in d_out, consumed
                                               // before the final out-gemm

  xsplit_kernel<<<dim3(2048), 256, 0, stream>>>(x, xhi, xlo);

  // mat order in WSP: 0=qf 1=qp 2=kf 3=kp 4=v 5=o
  wsplit_kernel<<<dim3(16, 16, 6), 256, 0, stream>>>(Wqf, Wqp, Wkf, Wkp, Wv, Wo, WSP);

  proj_kernel<<<dim3(Tt / 256, Hh, Bb * 2), 256, 0, stream>>>(
      xhi, xlo, WSP, bqf, bqp, bkf, bkp, qnh, knh);

  gemm_kernel<<<dim3((Bb * Tt) / 128, Dd / 128), 256, 0, stream>>>(
      xhi, xlo, WSP + (size_t)4 * 2097152, bv, vbuf);

  chunk_kv_kernel<<<dim3(NC, Hh, Bb), 256, 0, stream>>>(knh, vbuf, G);
  prefix_kernel<<<dim3(16, Hh, Bb), 256, 0, stream>>>(G);
  attn_chunk_kernel<<<dim3(NC, Hh, Bb), 256, 0, stream>>>(
      qnh, knh, vbuf, G, scale, qnh /*atthi*/, knh /*attlo*/);

  gemm_kernel<<<dim3((Bb * Tt) / 128, Dd / 128), 256, 0, stream>>>(
      qnh, knh, WSP + (size_t)5 * 2097152, bo, (float*)d_out);
}

// Round 10
// 405.039 us; speedup vs baseline: 1.0460x; 1.0460x over previous
//
#include <hip/hip_runtime.h>

// PureWaveAttention B=2,T=2048,D=1024,H=16,NW=64,HD=64 — fp32 I/O, all GEMMs
// on MFMA via 2-term fp16 split: a = hi + lo/2048 (lo stored pre-scaled x2048).
// C = hh(hi,hi) + mx(hi,lo + lo,hi)/2048. Rel err 2^-22 -> fp32-equivalent.
// Pipeline:
//  0) xsplit: x fp32 -> xhi/xlo fp16 (aliases G region, dead until chunk_kv)
//  0b) wsplit: W{qf,qp,kf,kp,v,o} fp32[k][n] -> Whi/Wlo fp16[n][k]
//  1) proj: qn/kn = normalize(sin((x@Wf+bf)*t + (x@Wp+bp))) -> fp16
//  2) vgemm: v = x@Wv+bv -> fp32 in d_out (consumed before out-gemm)
//  3) chunk_kv -> G; prefix -> M; attn_chunk -> att split fp16 (aliases qnh/knh)
//  4) outgemm: d_out = att@Wo+bo
// R10: proj 2x2 WAVE QUADRANTS (register-feasible form of R9's LDS-BW fix;
// R9 spilled: 256 acc VGPR -> WRITE_SIZE 172MB, 204us). Wave (wm,wn) owns
// 64 rows x 64 cols: F-tile wn, P-tile 2+wn, 2 row-groups. Per phase:
// 8 B-reads (was 16), 24 MFMA, acc 8xf32x16=128 VGPR (+A dbuf 64) ~220 VGPR.
// Per-CU LDS/phase 768cyc vs MFMA 384 -> ~50% ceiling (R8: 1280 -> 30%,
// matches measured 33%). F/P for a row live in sibling waves -> epilogue
// exchange via LDS (w into dead buf0/1, partial ss into buf2, one barrier).
// Schedule = R8 quad-buffer, vmcnt(4) barriers, no sched fences.
// gemm: R7 BAR_LG version (kept; best measured).
// ws (56 MB): Wsplit 24 | qnh 8 | knh 8 | G 16 (xhi/xlo alias G before chunk_kv)

#define Bb 2
#define Tt 2048
#define Dd 1024
#define Hh 16
#define NC 32

typedef _Float16 half_t;
typedef _Float16 half8 __attribute__((ext_vector_type(8)));
typedef _Float16 half4h __attribute__((ext_vector_type(4)));
typedef float f32x16 __attribute__((ext_vector_type(16)));

#define MFMA32(a, b, c) __builtin_amdgcn_mfma_f32_32x32x16_f16((a), (b), (c), 0, 0, 0)

// global_load_lds: per-lane global src, wave-uniform LDS base + lane*16.
#define GLL(G, L) __builtin_amdgcn_global_load_lds(                      \
    (const __attribute__((address_space(1))) void*)(G),                  \
    (__attribute__((address_space(3))) void*)(L), 16, 0, 0)

#define SCHED_FENCE() __builtin_amdgcn_sched_barrier(0)

// proj phase barrier: drain all but the 4 newest vmem ops (= this phase's
// GLLs). No sched fences (R7 lesson).
#define BARC() {                                                         \
    asm volatile("s_waitcnt vmcnt(4) lgkmcnt(0)" ::: "memory");          \
    __builtin_amdgcn_s_barrier(); }

// gemm phase barrier, LDS ordering only (vmem stays in flight) — R7 version.
#define BAR_LG() {                                                       \
    SCHED_FENCE();                                                       \
    asm volatile("s_waitcnt lgkmcnt(0)" ::: "memory");                   \
    __builtin_amdgcn_s_barrier();                                        \
    SCHED_FENCE(); }

// ---------------------------------------------------------------------------
// Kernel -1: split x fp32 -> xhi, xlo fp16 (lo pre-scaled x2048).
// ---------------------------------------------------------------------------
__global__ __launch_bounds__(256) void xsplit_kernel(
    const float* __restrict__ X, half_t* __restrict__ XHI, half_t* __restrict__ XLO)
{
  const size_t i = ((size_t)blockIdx.x * 256 + threadIdx.x) * 8;
  float4 a = *(const float4*)&X[i];
  float4 b = *(const float4*)&X[i + 4];
  const float av[8] = {a.x, a.y, a.z, a.w, b.x, b.y, b.z, b.w};
  half8 hv, lv;
  #pragma unroll
  for (int j = 0; j < 8; ++j) {
    half_t hx = (half_t)av[j];
    hv[j] = hx; lv[j] = (half_t)((av[j] - (float)hx) * 2048.f);
  }
  *(half8*)&XHI[i] = hv;
  *(half8*)&XLO[i] = lv;
}

// ---------------------------------------------------------------------------
// Kernel 0: split+transpose weights: W[k][n] fp32 -> hi[n][k], lo[n][k] fp16.
// Per matrix: hi at m*2097152 halves, lo at +1048576.
// ---------------------------------------------------------------------------
__global__ __launch_bounds__(256) void wsplit_kernel(
    const float* __restrict__ W0, const float* __restrict__ W1,
    const float* __restrict__ W2, const float* __restrict__ W3,
    const float* __restrict__ W4, const float* __restrict__ W5,
    half_t* __restrict__ WSP)
{
  __shared__ float Ld[64][68];
  const int tid = threadIdx.x;
  const int m = blockIdx.z;
  const float* W = (m == 0) ? W0 : (m == 1) ? W1 : (m == 2) ? W2
                 : (m == 3) ? W3 : (m == 4) ? W4 : W5;
  const int k0 = blockIdx.x * 64, n0 = blockIdx.y * 64;
  const int r = tid >> 2, c4 = (tid & 3) * 16;
  #pragma unroll
  for (int i = 0; i < 4; ++i)
    *(float4*)&Ld[r][c4 + i * 4] =
        *(const float4*)&W[(size_t)(k0 + r) * Dd + n0 + c4 + i * 4];
  __syncthreads();
  half_t* hi = WSP + (size_t)m * 2097152;
  half_t* lo = hi + 1048576;
  const int n = tid >> 2, kc = (tid & 3) * 16;
  half8 hv0, hv1, lv0, lv1;
  #pragma unroll
  for (int i = 0; i < 8; ++i) {
    float v0 = Ld[kc + i][n];
    half_t h0 = (half_t)v0;
    hv0[i] = h0; lv0[i] = (half_t)((v0 - (float)h0) * 2048.f);
    float v1 = Ld[kc + 8 + i][n];
    half_t h1 = (half_t)v1;
    hv1[i] = h1; lv1[i] = (half_t)((v1 - (float)h1) * 2048.f);
  }
  *(half8*)&hi[(size_t)(n0 + n) * Dd + k0 + kc]     = hv0;
  *(half8*)&hi[(size_t)(n0 + n) * Dd + k0 + kc + 8] = hv1;
  *(half8*)&lo[(size_t)(n0 + n) * Dd + k0 + kc]     = lv0;
  *(half8*)&lo[(size_t)(n0 + n) * Dd + k0 + kc + 8] = lv1;
}

// ---------------------------------------------------------------------------
// Kernel 1: proj. Block = 128 t-rows x (64 F | 64 P) cols for head h, pair p.
// Wave (wm=w>>1, wn=w&1): rows 64wm..+63 (2 groups, A in regs), F cols
// 32wn..+31 (B tile wn) and P cols 32wn..+31 (B tile 2+wn) -> 4 32x32 acc
// tiles x (hh,mx) = 128 VGPR. B QUAD-buffered via global_load_lds (stage 2
// phases ahead); phase = {LOADA8 A(p+1) | STAGE buf(p+2) | 24 MFMA |
// BARC vmcnt(4)}. 8 B-reads/phase/wave (half of R8).
// Epilogue: w -> LDS (dead buf0/1), per-row partial ss -> buf2; barrier;
// combine sibling-wave partials, normalize, write fp16.
// B LDS tile: [128 rows][64 halves]; row = 8x16B chunks [hi oct0..3|lo 0..3],
// chunk c at phys c^(row&7); per-lane GLOBAL source pre-swizzled to match.
// ---------------------------------------------------------------------------
__global__ __launch_bounds__(256, 2) void proj_kernel(
    const half_t* __restrict__ XHI, const half_t* __restrict__ XLO,
    const half_t* __restrict__ WSP,
    const float* __restrict__ bqf, const float* __restrict__ bqp,
    const float* __restrict__ bkf, const float* __restrict__ bkp,
    half_t* __restrict__ QNH, half_t* __restrict__ KNH)
{
  __shared__ __align__(16) half_t Bs[4][128][64];
  const int tid = threadIdx.x;
  const int mb = blockIdx.x, h = blockIdx.y;
  const int b = blockIdx.z >> 1, p = blockIdx.z & 1;
  const int t0 = mb * 128, row0 = b * Tt + t0, col0 = h * 64;
  const half_t* WF = WSP + (size_t)(2 * p) * 2097152;      // hi; lo at +1048576
  const half_t* WP = WSP + (size_t)(2 * p + 1) * 2097152;
  const float* BF = p ? bkf : bqf;
  const float* BP = p ? bkp : bqp;
  half_t* OUTH = p ? KNH : QNH;

  f32x16 hF[2], mF[2], hP[2], mP[2];
  #pragma unroll
  for (int i = 0; i < 2; ++i) {
    hF[i] = (f32x16)(0.f); mF[i] = (f32x16)(0.f);
    hP[i] = (f32x16)(0.f); mP[i] = (f32x16)(0.f);
  }

  const int lane = tid & 63, w = tid >> 6;
  const int rl = lane & 31, kq = lane >> 5;
  const int sw = rl & 7;
  const int wm = w >> 1, wn = w & 1;

  // A (x) sources: group0 row 64wm+rl, group1 +32; k-octets kq and 2+kq.
  const half_t* aHi0 = XHI + (size_t)(row0 + 64 * wm + rl) * Dd + kq * 8;
  const half_t* aLo0 = XLO + (size_t)(row0 + 64 * wm + rl) * Dd + kq * 8;
  const half_t* aHi1 = aHi0 + 32 * Dd;
  const half_t* aLo1 = aLo0 + 32 * Dd;

  // B staging sources (per-lane, inverse-swizzled chunk):
  const int lr8 = lane >> 3;                 // row-within-8
  const int lcc = (lane & 7) ^ lr8;          // logical chunk this lane fetches
  const int csel = (lcc & 3) * 8;            // k sub-offset (halves)
  const size_t loOff = (lcc >= 4) ? 1048576 : 0;
  const half_t* gb0 = WF + loOff + (size_t)(col0 + 8 * w + lr8) * Dd + csel;
  const half_t* gb1 = gb0 + 32 * Dd;
  const half_t* gb2 = WP + loOff + (size_t)(col0 + 8 * w + lr8) * Dd + csel;
  const half_t* gb3 = gb2 + 32 * Dd;

#define STAGE_PB(BI, K) {                          \
    GLL(gb0 + (K), &Bs[BI][8 * w][0]);             \
    GLL(gb1 + (K), &Bs[BI][32 + 8 * w][0]);        \
    GLL(gb2 + (K), &Bs[BI][64 + 8 * w][0]);        \
    GLL(gb3 + (K), &Bs[BI][96 + 8 * w][0]); }

// load both row-groups' A fragments for k-tile K into an 8-reg set
#define LOADA8(R00, R01, R02, R03, R10, R11, R12, R13, K) {  \
    R00 = *(const half8*)&aHi0[(K)];                         \
    R01 = *(const half8*)&aHi0[(K) + 16];                    \
    R02 = *(const half8*)&aLo0[(K)];                         \
    R03 = *(const half8*)&aLo0[(K) + 16];                    \
    R10 = *(const half8*)&aHi1[(K)];                         \
    R11 = *(const half8*)&aHi1[(K) + 16];                    \
    R12 = *(const half8*)&aLo1[(K)];                         \
    R13 = *(const half8*)&aLo1[(K) + 16]; }

// one 32-k tile: 8 B-reads (F tile wn, P tile 2+wn), 24 MFMA (2 row-groups)
#define KT_Q(A00, A01, A02, A03, A10, A11, A12, A13, BI) {             \
    { const int c0 = (kq ^ sw) * 8, c1 = ((4 + kq) ^ sw) * 8;          \
      half8 fh = *(const half8*)&Bs[BI][32 * wn + rl][c0];             \
      half8 fl = *(const half8*)&Bs[BI][32 * wn + rl][c1];             \
      half8 ph = *(const half8*)&Bs[BI][64 + 32 * wn + rl][c0];        \
      half8 pl = *(const half8*)&Bs[BI][64 + 32 * wn + rl][c1];        \
      hF[0] = MFMA32(A00, fh, hF[0]);                                  \
      mF[0] = MFMA32(A00, fl, mF[0]);                                  \
      mF[0] = MFMA32(A02, fh, mF[0]);                                  \
      hF[1] = MFMA32(A10, fh, hF[1]);                                  \
      mF[1] = MFMA32(A10, fl, mF[1]);                                  \
      mF[1] = MFMA32(A12, fh, mF[1]);                                  \
      hP[0] = MFMA32(A00, ph, hP[0]);                                  \
      mP[0] = MFMA32(A00, pl, mP[0]);                                  \
      mP[0] = MFMA32(A02, ph, mP[0]);                                  \
      hP[1] = MFMA32(A10, ph, hP[1]);                                  \
      mP[1] = MFMA32(A10, pl, mP[1]);                                  \
      mP[1] = MFMA32(A12, ph, mP[1]); }                                \
    { const int c0 = ((2 + kq) ^ sw) * 8, c1 = ((6 + kq) ^ sw) * 8;    \
      half8 fh = *(const half8*)&Bs[BI][32 * wn + rl][c0];             \
      half8 fl = *(const half8*)&Bs[BI][32 * wn + rl][c1];             \
      half8 ph = *(const half8*)&Bs[BI][64 + 32 * wn + rl][c0];        \
      half8 pl = *(const half8*)&Bs[BI][64 + 32 * wn + rl][c1];        \
      hF[0] = MFMA32(A01, fh, hF[0]);                                  \
      mF[0] = MFMA32(A01, fl, mF[0]);                                  \
      mF[0] = MFMA32(A03, fh, mF[0]);                                  \
      hF[1] = MFMA32(A11, fh, hF[1]);                                  \
      mF[1] = MFMA32(A11, fl, mF[1]);                                  \
      mF[1] = MFMA32(A13, fh, mF[1]);                                  \
      hP[0] = MFMA32(A01, ph, hP[0]);                                  \
      mP[0] = MFMA32(A01, pl, mP[0]);                                  \
      mP[0] = MFMA32(A03, ph, mP[0]);                                  \
      hP[1] = MFMA32(A11, ph, hP[1]);                                  \
      mP[1] = MFMA32(A11, pl, mP[1]);                                  \
      mP[1] = MFMA32(A13, ph, mP[1]); } }

  half8 c00, c01, c02, c03, c10, c11, c12, c13;
  half8 n00, n01, n02, n03, n10, n11, n12, n13;
  // prologue: stage buf0,buf1; load A(k=0).
  STAGE_PB(0, 0)
  STAGE_PB(1, 32)
  LOADA8(c00, c01, c02, c03, c10, c11, c12, c13, 0)
  BARC()

  #pragma unroll 1
  for (int k0 = 0; k0 < Dd; k0 += 128) {      // 4 phases (32-k each) per iter
    // phase a: compute buf0 (k0); A(k0+32); stage buf2 (k0+64)
    LOADA8(n00, n01, n02, n03, n10, n11, n12, n13, k0 + 32)
    STAGE_PB(2, k0 + 64)
    KT_Q(c00, c01, c02, c03, c10, c11, c12, c13, 0)
    BARC()
    // phase b: compute buf1 (k0+32); A(k0+64); stage buf3 (k0+96)
    LOADA8(c00, c01, c02, c03, c10, c11, c12, c13, k0 + 64)
    STAGE_PB(3, k0 + 96)
    KT_Q(n00, n01, n02, n03, n10, n11, n12, n13, 1)
    BARC()
    // phase c: compute buf2 (k0+64); A(k0+96); stage buf0 (k0+128)
    LOADA8(n00, n01, n02, n03, n10, n11, n12, n13, k0 + 96)
    if (k0 + 128 < Dd) { STAGE_PB(0, k0 + 128) }
    KT_Q(c00, c01, c02, c03, c10, c11, c12, c13, 2)
    BARC()
    // phase d: compute buf3 (k0+96); A(k0+128); stage buf1 (k0+160)
    if (k0 + 128 < Dd) { LOADA8(c00, c01, c02, c03, c10, c11, c12, c13, k0 + 128) }
    if (k0 + 160 < Dd) { STAGE_PB(1, k0 + 160) }
    KT_Q(n00, n01, n02, n03, n10, n11, n12, n13, 3)
    BARC()
  }
#undef STAGE_PB
#undef LOADA8
#undef KT_Q

  // ---- epilogue: cross-wave F/P normalize via LDS (bufs now dead) ----
  float* wbuf = (float*)&Bs[0][0][0];     // [128 rows][64 cols] f32 = 32 KB
  float* ssb  = (float*)&Bs[2][0][0];     // [2][128] f32 partial ss
  const float bf = BF[col0 + 32 * wn + rl];
  const float bp = BP[col0 + 32 * wn + rl];
  #pragma unroll
  for (int g = 0; g < 2; ++g) {
    #pragma unroll
    for (int j = 0; j < 16; ++j) {
      const int rtj = (j & 3) + 8 * (j >> 2) + 4 * kq;
      const int rowl = 64 * wm + 32 * g + rtj;
      const float tf = (float)(t0 + rowl);
      float f  = (g ? hF[1][j] : hF[0][j]) + (g ? mF[1][j] : mF[0][j]) * (1.f / 2048.f) + bf;
      float pp = (g ? hP[1][j] : hP[0][j]) + (g ? mP[1][j] : mP[0][j]) * (1.f / 2048.f) + bp;
      float w0 = sinf(fmaf(f, tf, pp));
      float ss = w0 * w0;
      ss += __shfl_xor(ss, 1); ss += __shfl_xor(ss, 2);
      ss += __shfl_xor(ss, 4); ss += __shfl_xor(ss, 8);
      ss += __shfl_xor(ss, 16);
      wbuf[rowl * 64 + 32 * wn + rl] = w0;
      if (rl == 0) ssb[wn * 128 + rowl] = ss;
    }
  }
  __syncthreads();
  #pragma unroll
  for (int g = 0; g < 2; ++g) {
    #pragma unroll
    for (int j = 0; j < 16; ++j) {
      const int rtj = (j & 3) + 8 * (j >> 2) + 4 * kq;
      const int rowl = 64 * wm + 32 * g + rtj;
      const float inv = 1.f / fmaxf(sqrtf(ssb[rowl] + ssb[128 + rowl]), 1e-12f);
      OUTH[((size_t)(b * Tt) + t0 + rowl) * Dd + col0 + 32 * wn + rl] =
          (half_t)(wbuf[rowl * 64 + 32 * wn + rl] * inv);
    }
  }
}

// ---------------------------------------------------------------------------
// Kernel 2/4: GEMM OUT[4096,1024] = A@W + bias. R2 structure (128x128 dbuf,
// row-per-thread ds_write staging, XOR-swz) with lgkm-only barriers: the 8
// global prefetch loads stay in flight across phase boundaries. (R7, kept.)
// ---------------------------------------------------------------------------
__global__ __launch_bounds__(256, 2) void gemm_kernel(
    const half_t* __restrict__ AHI, const half_t* __restrict__ ALO,
    const half_t* __restrict__ WHI,
    const float* __restrict__ BIAS, float* __restrict__ OUT)
{
  __shared__ __align__(16) half_t As[2][128][64];
  __shared__ __align__(16) half_t Bs[2][128][64];
  const int tid = threadIdx.x;
  const int m0 = blockIdx.x * 128, n0 = blockIdx.y * 128;

  f32x16 hh[4], mx[4];
  #pragma unroll
  for (int i = 0; i < 4; ++i) { hh[i] = (f32x16)(0.f); mx[i] = (f32x16)(0.f); }

  const int lane = tid & 63, w = tid >> 6;
  const int rl = lane & 31, kq = lane >> 5;
  const int sw = rl & 7;

  const int r = tid & 127, isB = tid >> 7;
  const int swr = r & 7;
  const half_t* srcHi = isB ? &WHI[(size_t)(n0 + r) * Dd]
                            : &AHI[(size_t)(m0 + r) * Dd];
  const half_t* srcLo = isB ? &WHI[1048576 + (size_t)(n0 + r) * Dd]
                            : &ALO[(size_t)(m0 + r) * Dd];
  half_t* dstRow = isB ? &Bs[0][r][0] : &As[0][r][0];
  const int pc0 = (0 ^ swr) * 8, pc1 = (1 ^ swr) * 8;
  const int pc2 = (2 ^ swr) * 8, pc3 = (3 ^ swr) * 8;
  const int pc4 = (4 ^ swr) * 8, pc5 = (5 ^ swr) * 8;
  const int pc6 = (6 ^ swr) * 8, pc7 = (7 ^ swr) * 8;

  half8 rg0, rg1, rg2, rg3, rg4, rg5, rg6, rg7;

#define G_LOADREGS(K)                                                          \
  rg0 = *(const half8*)&srcHi[(K)];      rg1 = *(const half8*)&srcHi[(K) + 8]; \
  rg2 = *(const half8*)&srcHi[(K) + 16]; rg3 = *(const half8*)&srcHi[(K) + 24];\
  rg4 = *(const half8*)&srcLo[(K)];      rg5 = *(const half8*)&srcLo[(K) + 8]; \
  rg6 = *(const half8*)&srcLo[(K) + 16]; rg7 = *(const half8*)&srcLo[(K) + 24];

#define G_WRITE(BI) {                                                     \
  half_t* d_ = dstRow + (BI) * 8192;                                      \
  *(half8*)&d_[pc0] = rg0; *(half8*)&d_[pc1] = rg1;                       \
  *(half8*)&d_[pc2] = rg2; *(half8*)&d_[pc3] = rg3;                       \
  *(half8*)&d_[pc4] = rg4; *(half8*)&d_[pc5] = rg5;                       \
  *(half8*)&d_[pc6] = rg6; *(half8*)&d_[pc7] = rg7; }

#define G_KT(BI)                                                          \
  _Pragma("unroll")                                                       \
  for (int ks = 0; ks < 2; ++ks) {                                        \
    half8 ahi = *(const half8*)&As[BI][32 * w + rl][((2 * ks + kq) ^ sw) * 8];       \
    half8 alo = *(const half8*)&As[BI][32 * w + rl][((4 + 2 * ks + kq) ^ sw) * 8];   \
    _Pragma("unroll")                                                     \
    for (int tn = 0; tn < 4; ++tn) {                                      \
      half8 bhi = *(const half8*)&Bs[BI][32 * tn + rl][((2 * ks + kq) ^ sw) * 8];    \
      half8 blo = *(const half8*)&Bs[BI][32 * tn + rl][((4 + 2 * ks + kq) ^ sw) * 8];\
      hh[tn] = MFMA32(ahi, bhi, hh[tn]);                                  \
      mx[tn] = MFMA32(ahi, blo, mx[tn]);                                  \
      mx[tn] = MFMA32(alo, bhi, mx[tn]);                                  \
    }                                                                     \
  }

  G_LOADREGS(0)
  G_WRITE(0)
  G_LOADREGS(32)
  BAR_LG()

  #pragma unroll 1
  for (int k0 = 0; k0 < Dd; k0 += 64) {
    G_KT(0)
    G_WRITE(1)
    if (k0 + 64 < Dd) { G_LOADREGS(k0 + 64) }
    BAR_LG()
    G_KT(1)
    if (k0 + 64 < Dd) { G_WRITE(0) }
    if (k0 + 96 < Dd) { G_LOADREGS(k0 + 96) }
    BAR_LG()
  }
#undef G_LOADREGS
#undef G_WRITE
#undef G_KT

  const float bb0 = BIAS[n0 + rl],      bb1 = BIAS[n0 + 32 + rl];
  const float bb2 = BIAS[n0 + 64 + rl], bb3 = BIAS[n0 + 96 + rl];
  #pragma unroll
  for (int j = 0; j < 16; ++j) {
    const int rtj = (j & 3) + 8 * (j >> 2) + 4 * kq;
    float* orow = &OUT[(size_t)(m0 + 32 * w + rtj) * Dd + n0];
    orow[rl]      = hh[0][j] + mx[0][j] * (1.f / 2048.f) + bb0;
    orow[32 + rl] = hh[1][j] + mx[1][j] * (1.f / 2048.f) + bb1;
    orow[64 + rl] = hh[2][j] + mx[2][j] * (1.f / 2048.f) + bb2;
    orow[96 + rl] = hh[3][j] + mx[3][j] * (1.f / 2048.f) + bb3;
  }
}

// ---------------------------------------------------------------------------
// Kernel 3a: G_c[w][d] = sum_{s in c} K[s][w]*V[s][d]. K from fp16, V fp32.
// ---------------------------------------------------------------------------
__global__ __launch_bounds__(256) void chunk_kv_kernel(
    const half_t* __restrict__ KNH, const float* __restrict__ V,
    float* __restrict__ G)
{
  __shared__ float Ks[64][64];
  __shared__ float Vs[64][64];
  const int tid = threadIdx.x;
  const int c = blockIdx.x, h = blockIdx.y, b = blockIdx.z;
  const int s0 = c * 64;
  const int lr = tid >> 2, lc = (tid & 3) * 16;
  {
    const half_t* krow = &KNH[(size_t)(b * Tt + s0 + lr) * Dd + h * 64 + lc];
    half8 ka = *(const half8*)&krow[0];
    half8 kb = *(const half8*)&krow[8];
    #pragma unroll
    for (int i = 0; i < 8; ++i) {
      Ks[lr][lc + i] = (float)ka[i];
      Ks[lr][lc + 8 + i] = (float)kb[i];
    }
    const float* vrow = &V[(size_t)(b * Tt + s0 + lr) * Dd + h * 64 + lc];
    #pragma unroll
    for (int i = 0; i < 4; ++i)
      *(float4*)&Vs[lr][lc + i * 4] = *(const float4*)&vrow[i * 4];
  }
  __syncthreads();

  const int ty = tid >> 4, tx = tid & 15;
  float g[4][4] = {{0.f}};
  #pragma unroll 4
  for (int s = 0; s < 64; ++s) {
    float4 kv = *(const float4*)&Ks[s][ty * 4];
    float4 vv = *(const float4*)&Vs[s][tx * 4];
    const float* k_ = (const float*)&kv;
    const float* v_ = (const float*)&vv;
    #pragma unroll
    for (int i = 0; i < 4; ++i)
      #pragma unroll
      for (int j = 0; j < 4; ++j)
        g[i][j] = fmaf(k_[i], v_[j], g[i][j]);
  }
  float* Gp = G + (((size_t)(b * Hh + h) * NC + c) << 12);
  #pragma unroll
  for (int i = 0; i < 4; ++i)
    *(float4*)&Gp[(ty * 4 + i) * 64 + tx * 4] =
        make_float4(g[i][0], g[i][1], g[i][2], g[i][3]);
}

// ---------------------------------------------------------------------------
// Kernel 3b: in-place exclusive prefix over NC chunk matrices per (b,h).
// 512 blocks; thread = 1 float, fully coalesced.
// ---------------------------------------------------------------------------
__global__ __launch_bounds__(256) void prefix_kernel(float* __restrict__ G)
{
  const int seg = blockIdx.x, h = blockIdx.y, b = blockIdx.z;
  float* base = G + (((size_t)(b * Hh + h) * NC) << 12) + seg * 256 + threadIdx.x;
  float acc = 0.f;
  #pragma unroll 4
  for (int c = 0; c < NC; ++c) {
    float* p = base + ((size_t)c << 12);
    const float g = *p;
    *p = acc;
    acc += g;
  }
}

// ---------------------------------------------------------------------------
// Kernel 3c: O_c = (Q_c M_c + tril(Q_c K_c^T) V_c) * scale/sqrt(t+1).
// Q,K from fp16; out split to fp16 hi/lo (lo x2048), aliasing qnh/knh.
// ---------------------------------------------------------------------------
__global__ __launch_bounds__(256) void attn_chunk_kernel(
    const half_t* __restrict__ QNH, const half_t* __restrict__ KNH,
    const float* __restrict__ V, const float* __restrict__ M,
    const float* __restrict__ SCALE,
    half_t* __restrict__ ATTHI, half_t* __restrict__ ATTLO)
{
  __shared__ float Qt[64][68];
  __shared__ float Kt[64][68];
  __shared__ float SM[64][68];
  __shared__ float Vs[64][64];
  const int tid = threadIdx.x;
  const int c = blockIdx.x, h = blockIdx.y, b = blockIdx.z;
  const int t0 = c * 64;
  const int lr = tid >> 2, lc = (tid & 3) * 16;
  {
    const half_t* qrow = &QNH[(size_t)(b * Tt + t0 + lr) * Dd + h * 64 + lc];
    const half_t* krow = &KNH[(size_t)(b * Tt + t0 + lr) * Dd + h * 64 + lc];
    half8 qa = *(const half8*)&qrow[0];
    half8 qb = *(const half8*)&qrow[8];
    half8 ka = *(const half8*)&krow[0];
    half8 kb = *(const half8*)&krow[8];
    #pragma unroll
    for (int i = 0; i < 8; ++i) {
      Qt[lc + i][lr] = (float)qa[i];     Qt[lc + 8 + i][lr] = (float)qb[i];
      Kt[lc + i][lr] = (float)ka[i];     Kt[lc + 8 + i][lr] = (float)kb[i];
    }
    const float* vrow = &V[(size_t)(b * Tt + t0 + lr) * Dd + h * 64 + lc];
    const float* mrow = &M[(((size_t)(b * Hh + h) * NC + c) << 12) + lr * 64 + lc];
    #pragma unroll
    for (int i = 0; i < 4; ++i) {
      *(float4*)&Vs[lr][lc + i * 4] = *(const float4*)&vrow[i * 4];
      *(float4*)&SM[lr][lc + i * 4] = *(const float4*)&mrow[i * 4];
    }
  }
  __syncthreads();

  const int ty = tid >> 4, tx = tid & 15;
  float o[4][4] = {{0.f}};
  float sc[4][4] = {{0.f}};

  #pragma unroll 4
  for (int w = 0; w < 64; ++w) {
    float4 qv = *(const float4*)&Qt[w][ty * 4];
    float4 mv = *(const float4*)&SM[w][tx * 4];
    float4 kv = *(const float4*)&Kt[w][tx * 4];
    const float* q_ = (const float*)&qv;
    const float* m_ = (const float*)&mv;
    const float* k_ = (const float*)&kv;
    #pragma unroll
    for (int i = 0; i < 4; ++i) {
      float qq = q_[i];
      #pragma unroll
      for (int j = 0; j < 4; ++j) {
        o[i][j]  = fmaf(qq, m_[j], o[i][j]);
        sc[i][j] = fmaf(qq, k_[j], sc[i][j]);
      }
    }
  }
  __syncthreads();

  #pragma unroll
  for (int i = 0; i < 4; ++i) {
    const int lt = ty * 4 + i;
    #pragma unroll
    for (int j = 0; j < 4; ++j) {
      const int ls = tx * 4 + j;
      SM[ls][lt] = (ls <= lt) ? sc[i][j] : 0.f;
    }
  }
  __syncthreads();

  #pragma unroll 4
  for (int s = 0; s < 64; ++s) {
    float4 sv = *(const float4*)&SM[s][ty * 4];
    float4 vv = *(const float4*)&Vs[s][tx * 4];
    const float* s_ = (const float*)&sv;
    const float* v_ = (const float*)&vv;
    #pragma unroll
    for (int i = 0; i < 4; ++i)
      #pragma unroll
      for (int j = 0; j < 4; ++j)
        o[i][j] = fmaf(s_[i], v_[j], o[i][j]);
  }

  const float sch = SCALE[h];
  #pragma unroll
  for (int i = 0; i < 4; ++i) {
    const int t = t0 + ty * 4 + i;
    const float fac = sch / sqrtf((float)(t + 1));
    half4h hv, lv;
    #pragma unroll
    for (int j = 0; j < 4; ++j) {
      float v = o[i][j] * fac;
      half_t hx = (half_t)v;
      hv[j] = hx; lv[j] = (half_t)((v - (float)hx) * 2048.f);
    }
    *(half4h*)&ATTHI[(size_t)(b * Tt + t) * Dd + h * 64 + tx * 4] = hv;
    *(half4h*)&ATTLO[(size_t)(b * Tt + t) * Dd + h * 64 + tx * 4] = lv;
  }
}

// ---------------------------------------------------------------------------
extern "C" void kernel_launch(void* const* d_in, const int* in_sizes, int n_in,
                              void* d_out, int out_size, void* d_ws, size_t ws_size,
                              hipStream_t stream) {
  const float* x   = (const float*)d_in[0];
  const float* Wqf = (const float*)d_in[1];
  const float* bqf = (const float*)d_in[2];
  const float* Wkf = (const float*)d_in[3];
  const float* bkf = (const float*)d_in[4];
  const float* Wqp = (const float*)d_in[5];
  const float* bqp = (const float*)d_in[6];
  const float* Wkp = (const float*)d_in[7];
  const float* bkp = (const float*)d_in[8];
  const float* Wv  = (const float*)d_in[9];
  const float* bv  = (const float*)d_in[10];
  const float* Wo  = (const float*)d_in[11];
  const float* bo  = (const float*)d_in[12];
  const float* scale = (const float*)d_in[13];

  // ws layout (56 MB): Wsplit 24 MB | qnh 8 MB | knh 8 MB | G 16 MB
  half_t* WSP = (half_t*)d_ws;                 // 6 mats x (hi 1M + lo 1M) halves
  half_t* qnh = WSP + 12582912;                // 4,194,304 halves
  half_t* knh = qnh + 4194304;
  float*  G   = (float*)(knh + 4194304);
  half_t* xhi = (half_t*)G;                    // x halves alias G: dead before
  half_t* xlo = xhi + 4194304;                 // chunk_kv writes G
  float*  vbuf = (float*)d_out;                // v lives in d_out, consumed
                                               // before the final out-gemm

  xsplit_kernel<<<dim3(2048), 256, 0, stream>>>(x, xhi, xlo);

  // mat order in WSP: 0=qf 1=qp 2=kf 3=kp 4=v 5=o
  wsplit_kernel<<<dim3(16, 16, 6), 256, 0, stream>>>(Wqf, Wqp, Wkf, Wkp, Wv, Wo, WSP);

  proj_kernel<<<dim3(Tt / 128, Hh, Bb * 2), 256, 0, stream>>>(
      xhi, xlo, WSP, bqf, bqp, bkf, bkp, qnh, knh);

  gemm_kernel<<<dim3((Bb * Tt) / 128, Dd / 128), 256, 0, stream>>>(
      xhi, xlo, WSP + (size_t)4 * 2097152, bv, vbuf);

  chunk_kv_kernel<<<dim3(NC, Hh, Bb), 256, 0, stream>>>(knh, vbuf, G);
  prefix_kernel<<<dim3(16, Hh, Bb), 256, 0, stream>>>(G);
  attn_chunk_kernel<<<dim3(NC, Hh, Bb), 256, 0, stream>>>(
      qnh, knh, vbuf, G, scale, qnh /*atthi*/, knh /*attlo*/);

  gemm_kernel<<<dim3((Bb * Tt) / 128, Dd / 128), 256, 0, stream>>>(
      qnh, knh, WSP + (size_t)5 * 2097152, bo, (float*)d_out);
}

// Round 11
// 379.140 us; speedup vs baseline: 1.1174x; 1.0683x over previous
//
#include <hip/hip_runtime.h>

// PureWaveAttention B=2,T=2048,D=1024,H=16,NW=64,HD=64 — fp32 I/O, all GEMMs
// on MFMA via 2-term fp16 split: a = hi + lo/2048 (lo stored pre-scaled x2048).
// C = hh(hi,hi) + mx(hi,lo + lo,hi)/2048. Rel err 2^-22 -> fp32-equivalent.
// Pipeline:
//  0) xsplit: x fp32 -> xhi/xlo fp16 (aliases G region, dead until chunk_kv)
//  0b) wsplit: W{qf,qp,kf,kp,v,o} fp32[k][n] -> Whi/Wlo fp16[n][k]
//  1) proj: qn/kn = normalize(sin((x@Wf+bf)*t + (x@Wp+bp))) -> fp16
//  2) vgemm: v = x@Wv+bv -> fp32 in d_out (consumed before out-gemm)
//  3) chunk_kv -> G; prefix -> M; attn_chunk -> att split fp16 (aliases qnh/knh)
//  4) outgemm: d_out = att@Wo+bo
// R11: proj = R8 verbatim (best measured 137us; R9 spilled, R10 falsified the
// LDS-BW theory — proj is phase-serialization-bound, frozen). NEW: gemm
// N-tile 64 -> grid (32,16)=512 blocks = 2 blocks/CU (was 256 = 1/CU, no
// cross-block latency hiding). LDS As 32KB + Bs 16KB = 48KB -> 2 blocks fit;
// acc 2x(hh,mx) = 64 VGPR. Staging: threads 0-127 one A row; threads 128-255
// HALF a B row (kh=tid&1: hi-chunks 0-3 or lo-chunks 4-7). Same dbuf +
// BAR_LG schedule and XOR swizzle ((32n+rl)&7 == rl&7 invariant holds).
// ws (56 MB): Wsplit 24 | qnh 8 | knh 8 | G 16 (xhi/xlo alias G before chunk_kv)

#define Bb 2
#define Tt 2048
#define Dd 1024
#define Hh 16
#define NC 32

typedef _Float16 half_t;
typedef _Float16 half8 __attribute__((ext_vector_type(8)));
typedef _Float16 half4h __attribute__((ext_vector_type(4)));
typedef float f32x16 __attribute__((ext_vector_type(16)));

#define MFMA32(a, b, c) __builtin_amdgcn_mfma_f32_32x32x16_f16((a), (b), (c), 0, 0, 0)

// global_load_lds: per-lane global src, wave-uniform LDS base + lane*16.
#define GLL(G, L) __builtin_amdgcn_global_load_lds(                      \
    (const __attribute__((address_space(1))) void*)(G),                  \
    (__attribute__((address_space(3))) void*)(L), 16, 0, 0)

#define SCHED_FENCE() __builtin_amdgcn_sched_barrier(0)

// proj phase barrier: drain all but the 4 newest vmem ops (= this phase's
// GLLs). No sched fences (R7 lesson).
#define BARC() {                                                         \
    asm volatile("s_waitcnt vmcnt(4) lgkmcnt(0)" ::: "memory");          \
    __builtin_amdgcn_s_barrier(); }

// gemm phase barrier, LDS ordering only (vmem stays in flight) — R7 version.
#define BAR_LG() {                                                       \
    SCHED_FENCE();                                                       \
    asm volatile("s_waitcnt lgkmcnt(0)" ::: "memory");                   \
    __builtin_amdgcn_s_barrier();                                        \
    SCHED_FENCE(); }

// ---------------------------------------------------------------------------
// Kernel -1: split x fp32 -> xhi, xlo fp16 (lo pre-scaled x2048).
// ---------------------------------------------------------------------------
__global__ __launch_bounds__(256) void xsplit_kernel(
    const float* __restrict__ X, half_t* __restrict__ XHI, half_t* __restrict__ XLO)
{
  const size_t i = ((size_t)blockIdx.x * 256 + threadIdx.x) * 8;
  float4 a = *(const float4*)&X[i];
  float4 b = *(const float4*)&X[i + 4];
  const float av[8] = {a.x, a.y, a.z, a.w, b.x, b.y, b.z, b.w};
  half8 hv, lv;
  #pragma unroll
  for (int j = 0; j < 8; ++j) {
    half_t hx = (half_t)av[j];
    hv[j] = hx; lv[j] = (half_t)((av[j] - (float)hx) * 2048.f);
  }
  *(half8*)&XHI[i] = hv;
  *(half8*)&XLO[i] = lv;
}

// ---------------------------------------------------------------------------
// Kernel 0: split+transpose weights: W[k][n] fp32 -> hi[n][k], lo[n][k] fp16.
// Per matrix: hi at m*2097152 halves, lo at +1048576.
// ---------------------------------------------------------------------------
__global__ __launch_bounds__(256) void wsplit_kernel(
    const float* __restrict__ W0, const float* __restrict__ W1,
    const float* __restrict__ W2, const float* __restrict__ W3,
    const float* __restrict__ W4, const float* __restrict__ W5,
    half_t* __restrict__ WSP)
{
  __shared__ float Ld[64][68];
  const int tid = threadIdx.x;
  const int m = blockIdx.z;
  const float* W = (m == 0) ? W0 : (m == 1) ? W1 : (m == 2) ? W2
                 : (m == 3) ? W3 : (m == 4) ? W4 : W5;
  const int k0 = blockIdx.x * 64, n0 = blockIdx.y * 64;
  const int r = tid >> 2, c4 = (tid & 3) * 16;
  #pragma unroll
  for (int i = 0; i < 4; ++i)
    *(float4*)&Ld[r][c4 + i * 4] =
        *(const float4*)&W[(size_t)(k0 + r) * Dd + n0 + c4 + i * 4];
  __syncthreads();
  half_t* hi = WSP + (size_t)m * 2097152;
  half_t* lo = hi + 1048576;
  const int n = tid >> 2, kc = (tid & 3) * 16;
  half8 hv0, hv1, lv0, lv1;
  #pragma unroll
  for (int i = 0; i < 8; ++i) {
    float v0 = Ld[kc + i][n];
    half_t h0 = (half_t)v0;
    hv0[i] = h0; lv0[i] = (half_t)((v0 - (float)h0) * 2048.f);
    float v1 = Ld[kc + 8 + i][n];
    half_t h1 = (half_t)v1;
    hv1[i] = h1; lv1[i] = (half_t)((v1 - (float)h1) * 2048.f);
  }
  *(half8*)&hi[(size_t)(n0 + n) * Dd + k0 + kc]     = hv0;
  *(half8*)&hi[(size_t)(n0 + n) * Dd + k0 + kc + 8] = hv1;
  *(half8*)&lo[(size_t)(n0 + n) * Dd + k0 + kc]     = lv0;
  *(half8*)&lo[(size_t)(n0 + n) * Dd + k0 + kc + 8] = lv1;
}

// ---------------------------------------------------------------------------
// Kernel 1: proj (R8, frozen). Block = 128 t-rows x (64 F | 64 P) cols.
// Wave w: A rows 32w..+31 in REGISTERS; B QUAD-buffered in LDS via
// global_load_lds (stage 2 phases ahead). Phase: {LOADA A(p+1) | STAGE GLL
// buf(p+2) | 24 MFMA on buf(p%4) | BARC vmcnt(4)}.
// B LDS tile: [128 rows][64 halves]; row = 8x16B chunks [hi oct0..3|lo 0..3],
// chunk c at phys c^(row&7); per-lane GLOBAL source pre-swizzled to match.
// ---------------------------------------------------------------------------
__global__ __launch_bounds__(256, 2) void proj_kernel(
    const half_t* __restrict__ XHI, const half_t* __restrict__ XLO,
    const half_t* __restrict__ WSP,
    const float* __restrict__ bqf, const float* __restrict__ bqp,
    const float* __restrict__ bkf, const float* __restrict__ bkp,
    half_t* __restrict__ QNH, half_t* __restrict__ KNH)
{
  __shared__ __align__(16) half_t Bs[4][128][64];
  const int tid = threadIdx.x;
  const int mb = blockIdx.x, h = blockIdx.y;
  const int b = blockIdx.z >> 1, p = blockIdx.z & 1;
  const int t0 = mb * 128, row0 = b * Tt + t0, col0 = h * 64;
  const half_t* WF = WSP + (size_t)(2 * p) * 2097152;      // hi; lo at +1048576
  const half_t* WP = WSP + (size_t)(2 * p + 1) * 2097152;
  const float* BF = p ? bkf : bqf;
  const float* BP = p ? bkp : bqp;
  half_t* OUTH = p ? KNH : QNH;

  f32x16 hh[4], mx[4];
  #pragma unroll
  for (int i = 0; i < 4; ++i) { hh[i] = (f32x16)(0.f); mx[i] = (f32x16)(0.f); }

  const int lane = tid & 63, w = tid >> 6;
  const int rl = lane & 31, kq = lane >> 5;
  const int sw = rl & 7;

  // A (x) fragment sources: lane owns row 32w+rl, k-octets kq and 2+kq.
  const half_t* aHi = XHI + (size_t)(row0 + 32 * w + rl) * Dd + kq * 8;
  const half_t* aLo = XLO + (size_t)(row0 + 32 * w + rl) * Dd + kq * 8;

  // B staging sources (per-lane, inverse-swizzled chunk):
  const int lr8 = lane >> 3;                 // row-within-8
  const int lcc = (lane & 7) ^ lr8;          // logical chunk this lane fetches
  const int csel = (lcc & 3) * 8;            // k sub-offset (halves)
  const size_t loOff = (lcc >= 4) ? 1048576 : 0;
  const half_t* gb0 = WF + loOff + (size_t)(col0 + 8 * w + lr8) * Dd + csel;
  const half_t* gb1 = gb0 + 32 * Dd;
  const half_t* gb2 = WP + loOff + (size_t)(col0 + 8 * w + lr8) * Dd + csel;
  const half_t* gb3 = gb2 + 32 * Dd;

#define STAGE_PB(BI, K) {                          \
    GLL(gb0 + (K), &Bs[BI][8 * w][0]);             \
    GLL(gb1 + (K), &Bs[BI][32 + 8 * w][0]);        \
    GLL(gb2 + (K), &Bs[BI][64 + 8 * w][0]);        \
    GLL(gb3 + (K), &Bs[BI][96 + 8 * w][0]); }

#define LOADA(H0, H1, L0, L1, K) {                 \
    H0 = *(const half8*)&aHi[(K)];                 \
    H1 = *(const half8*)&aHi[(K) + 16];            \
    L0 = *(const half8*)&aLo[(K)];                 \
    L1 = *(const half8*)&aLo[(K) + 16]; }

#define KT_P(H0, H1, L0, L1, BI) {                                     \
    { const int c0 = (kq ^ sw) * 8, c1 = ((4 + kq) ^ sw) * 8;          \
      _Pragma("unroll")                                                \
      for (int tn = 0; tn < 4; ++tn) {                                 \
        half8 bh = *(const half8*)&Bs[BI][32 * tn + rl][c0];           \
        half8 bl = *(const half8*)&Bs[BI][32 * tn + rl][c1];           \
        hh[tn] = MFMA32(H0, bh, hh[tn]);                               \
        mx[tn] = MFMA32(H0, bl, mx[tn]);                               \
        mx[tn] = MFMA32(L0, bh, mx[tn]); } }                           \
    { const int c0 = (((2 + kq)) ^ sw) * 8, c1 = ((6 + kq) ^ sw) * 8;  \
      _Pragma("unroll")                                                \
      for (int tn = 0; tn < 4; ++tn) {                                 \
        half8 bh = *(const half8*)&Bs[BI][32 * tn + rl][c0];           \
        half8 bl = *(const half8*)&Bs[BI][32 * tn + rl][c1];           \
        hh[tn] = MFMA32(H1, bh, hh[tn]);                               \
        mx[tn] = MFMA32(H1, bl, mx[tn]);                               \
        mx[tn] = MFMA32(L1, bh, mx[tn]); } } }

  half8 ah0c, ah1c, al0c, al1c, ah0n, ah1n, al0n, al1n;
  // prologue: stage buf0,buf1; load A(k=0).
  STAGE_PB(0, 0)
  STAGE_PB(1, 32)
  LOADA(ah0c, ah1c, al0c, al1c, 0)
  BARC()

  #pragma unroll 1
  for (int k0 = 0; k0 < Dd; k0 += 128) {      // 4 phases (32-k each) per iter
    // phase a: compute buf0 (k0); A(k0+32); stage buf2 (k0+64)
    LOADA(ah0n, ah1n, al0n, al1n, k0 + 32)
    STAGE_PB(2, k0 + 64)
    KT_P(ah0c, ah1c, al0c, al1c, 0)
    BARC()
    // phase b: compute buf1 (k0+32); A(k0+64); stage buf3 (k0+96)
    LOADA(ah0c, ah1c, al0c, al1c, k0 + 64)
    STAGE_PB(3, k0 + 96)
    KT_P(ah0n, ah1n, al0n, al1n, 1)
    BARC()
    // phase c: compute buf2 (k0+64); A(k0+96); stage buf0 (k0+128)
    LOADA(ah0n, ah1n, al0n, al1n, k0 + 96)
    if (k0 + 128 < Dd) { STAGE_PB(0, k0 + 128) }
    KT_P(ah0c, ah1c, al0c, al1c, 2)
    BARC()
    // phase d: compute buf3 (k0+96); A(k0+128); stage buf1 (k0+160)
    if (k0 + 128 < Dd) { LOADA(ah0c, ah1c, al0c, al1c, k0 + 128) }
    if (k0 + 160 < Dd) { STAGE_PB(1, k0 + 160) }
    KT_P(ah0n, ah1n, al0n, al1n, 3)
    BARC()
  }
#undef STAGE_PB
#undef LOADA
#undef KT_P

  const float bf0 = BF[col0 + rl], bf1 = BF[col0 + 32 + rl];
  const float bp0 = BP[col0 + rl], bp1 = BP[col0 + 32 + rl];
  #pragma unroll
  for (int j = 0; j < 16; ++j) {
    const int rtj = (j & 3) + 8 * (j >> 2) + 4 * kq;  // row within 32-tile
    const float tf = (float)(t0 + 32 * w + rtj);
    float f0 = hh[0][j] + mx[0][j] * (1.f / 2048.f) + bf0;
    float f1 = hh[1][j] + mx[1][j] * (1.f / 2048.f) + bf1;
    float p0 = hh[2][j] + mx[2][j] * (1.f / 2048.f) + bp0;
    float p1 = hh[3][j] + mx[3][j] * (1.f / 2048.f) + bp1;
    float w0 = sinf(fmaf(f0, tf, p0));
    float w1 = sinf(fmaf(f1, tf, p1));
    float ss = w0 * w0 + w1 * w1;
    ss += __shfl_xor(ss, 1); ss += __shfl_xor(ss, 2);
    ss += __shfl_xor(ss, 4); ss += __shfl_xor(ss, 8);
    ss += __shfl_xor(ss, 16);
    const float inv = 1.f / fmaxf(sqrtf(ss), 1e-12f);
    half_t* op = &OUTH[((size_t)(b * Tt) + t0 + 32 * w + rtj) * Dd + col0];
    op[rl]      = (half_t)(w0 * inv);
    op[32 + rl] = (half_t)(w1 * inv);
  }
}

// ---------------------------------------------------------------------------
// Kernel 2/4: GEMM OUT[4096,1024] = A@W + bias. Tile 128M x 64N -> grid
// (32,16)=512 blocks = 2/CU (was 128x128, 256 blocks = 1/CU). Dbuf,
// BAR_LG barriers. Staging: threads 0-127 one A row (8 chunks); threads
// 128-255 half a B row (kh=tid&1: hi chunks 0-3 or lo chunks 4-7).
// Wave w: A rows 32w..+31, both B col-tiles (2 acc pairs).
// ---------------------------------------------------------------------------
__global__ __launch_bounds__(256, 2) void gemm_kernel(
    const half_t* __restrict__ AHI, const half_t* __restrict__ ALO,
    const half_t* __restrict__ WHI,
    const float* __restrict__ BIAS, float* __restrict__ OUT)
{
  __shared__ __align__(16) half_t As[2][128][64];
  __shared__ __align__(16) half_t Bs[2][64][64];
  const int tid = threadIdx.x;
  const int m0 = blockIdx.x * 128, n0 = blockIdx.y * 64;

  f32x16 hh[2], mx[2];
  #pragma unroll
  for (int i = 0; i < 2; ++i) { hh[i] = (f32x16)(0.f); mx[i] = (f32x16)(0.f); }

  const int lane = tid & 63, w = tid >> 6;
  const int rl = lane & 31, kq = lane >> 5;
  const int sw = rl & 7;

  const int isB = tid >> 7;
  const int ra = tid & 127;              // A row (isB=0)
  const int rb = (tid & 127) >> 1;       // B row (isB=1)
  const int kh = tid & 1;                // B half: 0=hi chunks 0-3, 1=lo 4-7
  const half_t* sHi;
  const half_t* sLo;
  half_t* dRow;
  int bufStride, swz;
  if (!isB) {
    sHi = &AHI[(size_t)(m0 + ra) * Dd];
    sLo = &ALO[(size_t)(m0 + ra) * Dd];
    dRow = &As[0][ra][0]; bufStride = 8192; swz = ra & 7;
  } else {
    const half_t* wb = WHI + (kh ? 1048576 : 0) + (size_t)(n0 + rb) * Dd;
    sHi = wb; sLo = wb;
    dRow = &Bs[0][rb][0]; bufStride = 4096; swz = rb & 7;
  }
  const int q0 = ((isB ? 4 * kh + 0 : 0) ^ swz) * 8;
  const int q1 = ((isB ? 4 * kh + 1 : 1) ^ swz) * 8;
  const int q2 = ((isB ? 4 * kh + 2 : 2) ^ swz) * 8;
  const int q3 = ((isB ? 4 * kh + 3 : 3) ^ swz) * 8;
  const int q4 = ((4) ^ swz) * 8, q5 = ((5) ^ swz) * 8;
  const int q6 = ((6) ^ swz) * 8, q7 = ((7) ^ swz) * 8;

  half8 rg0, rg1, rg2, rg3, rg4, rg5, rg6, rg7;

#define G_LOADREGS(K) {                                                        \
  rg0 = *(const half8*)&sHi[(K)];      rg1 = *(const half8*)&sHi[(K) + 8];     \
  rg2 = *(const half8*)&sHi[(K) + 16]; rg3 = *(const half8*)&sHi[(K) + 24];    \
  if (!isB) {                                                                  \
    rg4 = *(const half8*)&sLo[(K)];      rg5 = *(const half8*)&sLo[(K) + 8];   \
    rg6 = *(const half8*)&sLo[(K) + 16]; rg7 = *(const half8*)&sLo[(K) + 24];  \
  } }

#define G_WRITE(BI) {                                                    \
  half_t* d_ = dRow + (BI) * bufStride;                                  \
  *(half8*)&d_[q0] = rg0; *(half8*)&d_[q1] = rg1;                        \
  *(half8*)&d_[q2] = rg2; *(half8*)&d_[q3] = rg3;                        \
  if (!isB) {                                                            \
    *(half8*)&d_[q4] = rg4; *(half8*)&d_[q5] = rg5;                      \
    *(half8*)&d_[q6] = rg6; *(half8*)&d_[q7] = rg7;                      \
  } }

#define G_KT(BI)                                                          \
  _Pragma("unroll")                                                       \
  for (int ks = 0; ks < 2; ++ks) {                                        \
    const int ch = ((2 * ks + kq) ^ sw) * 8;                              \
    const int cl = ((4 + 2 * ks + kq) ^ sw) * 8;                          \
    half8 ahi = *(const half8*)&As[BI][32 * w + rl][ch];                  \
    half8 alo = *(const half8*)&As[BI][32 * w + rl][cl];                  \
    _Pragma("unroll")                                                     \
    for (int tn = 0; tn < 2; ++tn) {                                      \
      half8 bhi = *(const half8*)&Bs[BI][32 * tn + rl][ch];               \
      half8 blo = *(const half8*)&Bs[BI][32 * tn + rl][cl];               \
      hh[tn] = MFMA32(ahi, bhi, hh[tn]);                                  \
      mx[tn] = MFMA32(ahi, blo, mx[tn]);                                  \
      mx[tn] = MFMA32(alo, bhi, mx[tn]);                                  \
    }                                                                     \
  }

  G_LOADREGS(0)
  G_WRITE(0)
  G_LOADREGS(32)
  BAR_LG()

  #pragma unroll 1
  for (int k0 = 0; k0 < Dd; k0 += 64) {
    G_KT(0)
    G_WRITE(1)
    if (k0 + 64 < Dd) { G_LOADREGS(k0 + 64) }
    BAR_LG()
    G_KT(1)
    if (k0 + 64 < Dd) { G_WRITE(0) }
    if (k0 + 96 < Dd) { G_LOADREGS(k0 + 96) }
    BAR_LG()
  }
#undef G_LOADREGS
#undef G_WRITE
#undef G_KT

  const float bb0 = BIAS[n0 + rl], bb1 = BIAS[n0 + 32 + rl];
  #pragma unroll
  for (int j = 0; j < 16; ++j) {
    const int rtj = (j & 3) + 8 * (j >> 2) + 4 * kq;
    float* orow = &OUT[(size_t)(m0 + 32 * w + rtj) * Dd + n0];
    orow[rl]      = hh[0][j] + mx[0][j] * (1.f / 2048.f) + bb0;
    orow[32 + rl] = hh[1][j] + mx[1][j] * (1.f / 2048.f) + bb1;
  }
}

// ---------------------------------------------------------------------------
// Kernel 3a: G_c[w][d] = sum_{s in c} K[s][w]*V[s][d]. K from fp16, V fp32.
// ---------------------------------------------------------------------------
__global__ __launch_bounds__(256) void chunk_kv_kernel(
    const half_t* __restrict__ KNH, const float* __restrict__ V,
    float* __restrict__ G)
{
  __shared__ float Ks[64][64];
  __shared__ float Vs[64][64];
  const int tid = threadIdx.x;
  const int c = blockIdx.x, h = blockIdx.y, b = blockIdx.z;
  const int s0 = c * 64;
  const int lr = tid >> 2, lc = (tid & 3) * 16;
  {
    const half_t* krow = &KNH[(size_t)(b * Tt + s0 + lr) * Dd + h * 64 + lc];
    half8 ka = *(const half8*)&krow[0];
    half8 kb = *(const half8*)&krow[8];
    #pragma unroll
    for (int i = 0; i < 8; ++i) {
      Ks[lr][lc + i] = (float)ka[i];
      Ks[lr][lc + 8 + i] = (float)kb[i];
    }
    const float* vrow = &V[(size_t)(b * Tt + s0 + lr) * Dd + h * 64 + lc];
    #pragma unroll
    for (int i = 0; i < 4; ++i)
      *(float4*)&Vs[lr][lc + i * 4] = *(const float4*)&vrow[i * 4];
  }
  __syncthreads();

  const int ty = tid >> 4, tx = tid & 15;
  float g[4][4] = {{0.f}};
  #pragma unroll 4
  for (int s = 0; s < 64; ++s) {
    float4 kv = *(const float4*)&Ks[s][ty * 4];
    float4 vv = *(const float4*)&Vs[s][tx * 4];
    const float* k_ = (const float*)&kv;
    const float* v_ = (const float*)&vv;
    #pragma unroll
    for (int i = 0; i < 4; ++i)
      #pragma unroll
      for (int j = 0; j < 4; ++j)
        g[i][j] = fmaf(k_[i], v_[j], g[i][j]);
  }
  float* Gp = G + (((size_t)(b * Hh + h) * NC + c) << 12);
  #pragma unroll
  for (int i = 0; i < 4; ++i)
    *(float4*)&Gp[(ty * 4 + i) * 64 + tx * 4] =
        make_float4(g[i][0], g[i][1], g[i][2], g[i][3]);
}

// ---------------------------------------------------------------------------
// Kernel 3b: in-place exclusive prefix over NC chunk matrices per (b,h).
// 512 blocks; thread = 1 float, fully coalesced.
// ---------------------------------------------------------------------------
__global__ __launch_bounds__(256) void prefix_kernel(float* __restrict__ G)
{
  const int seg = blockIdx.x, h = blockIdx.y, b = blockIdx.z;
  float* base = G + (((size_t)(b * Hh + h) * NC) << 12) + seg * 256 + threadIdx.x;
  float acc = 0.f;
  #pragma unroll 4
  for (int c = 0; c < NC; ++c) {
    float* p = base + ((size_t)c << 12);
    const float g = *p;
    *p = acc;
    acc += g;
  }
}

// ---------------------------------------------------------------------------
// Kernel 3c: O_c = (Q_c M_c + tril(Q_c K_c^T) V_c) * scale/sqrt(t+1).
// Q,K from fp16; out split to fp16 hi/lo (lo x2048), aliasing qnh/knh.
// ---------------------------------------------------------------------------
__global__ __launch_bounds__(256) void attn_chunk_kernel(
    const half_t* __restrict__ QNH, const half_t* __restrict__ KNH,
    const float* __restrict__ V, const float* __restrict__ M,
    const float* __restrict__ SCALE,
    half_t* __restrict__ ATTHI, half_t* __restrict__ ATTLO)
{
  __shared__ float Qt[64][68];
  __shared__ float Kt[64][68];
  __shared__ float SM[64][68];
  __shared__ float Vs[64][64];
  const int tid = threadIdx.x;
  const int c = blockIdx.x, h = blockIdx.y, b = blockIdx.z;
  const int t0 = c * 64;
  const int lr = tid >> 2, lc = (tid & 3) * 16;
  {
    const half_t* qrow = &QNH[(size_t)(b * Tt + t0 + lr) * Dd + h * 64 + lc];
    const half_t* krow = &KNH[(size_t)(b * Tt + t0 + lr) * Dd + h * 64 + lc];
    half8 qa = *(const half8*)&qrow[0];
    half8 qb = *(const half8*)&qrow[8];
    half8 ka = *(const half8*)&krow[0];
    half8 kb = *(const half8*)&krow[8];
    #pragma unroll
    for (int i = 0; i < 8; ++i) {
      Qt[lc + i][lr] = (float)qa[i];     Qt[lc + 8 + i][lr] = (float)qb[i];
      Kt[lc + i][lr] = (float)ka[i];     Kt[lc + 8 + i][lr] = (float)kb[i];
    }
    const float* vrow = &V[(size_t)(b * Tt + t0 + lr) * Dd + h * 64 + lc];
    const float* mrow = &M[(((size_t)(b * Hh + h) * NC + c) << 12) + lr * 64 + lc];
    #pragma unroll
    for (int i = 0; i < 4; ++i) {
      *(float4*)&Vs[lr][lc + i * 4] = *(const float4*)&vrow[i * 4];
      *(float4*)&SM[lr][lc + i * 4] = *(const float4*)&mrow[i * 4];
    }
  }
  __syncthreads();

  const int ty = tid >> 4, tx = tid & 15;
  float o[4][4] = {{0.f}};
  float sc[4][4] = {{0.f}};

  #pragma unroll 4
  for (int w = 0; w < 64; ++w) {
    float4 qv = *(const float4*)&Qt[w][ty * 4];
    float4 mv = *(const float4*)&SM[w][tx * 4];
    float4 kv = *(const float4*)&Kt[w][tx * 4];
    const float* q_ = (const float*)&qv;
    const float* m_ = (const float*)&mv;
    const float* k_ = (const float*)&kv;
    #pragma unroll
    for (int i = 0; i < 4; ++i) {
      float qq = q_[i];
      #pragma unroll
      for (int j = 0; j < 4; ++j) {
        o[i][j]  = fmaf(qq, m_[j], o[i][j]);
        sc[i][j] = fmaf(qq, k_[j], sc[i][j]);
      }
    }
  }
  __syncthreads();

  #pragma unroll
  for (int i = 0; i < 4; ++i) {
    const int lt = ty * 4 + i;
    #pragma unroll
    for (int j = 0; j < 4; ++j) {
      const int ls = tx * 4 + j;
      SM[ls][lt] = (ls <= lt) ? sc[i][j] : 0.f;
    }
  }
  __syncthreads();

  #pragma unroll 4
  for (int s = 0; s < 64; ++s) {
    float4 sv = *(const float4*)&SM[s][ty * 4];
    float4 vv = *(const float4*)&Vs[s][tx * 4];
    const float* s_ = (const float*)&sv;
    const float* v_ = (const float*)&vv;
    #pragma unroll
    for (int i = 0; i < 4; ++i)
      #pragma unroll
      for (int j = 0; j < 4; ++j)
        o[i][j] = fmaf(s_[i], v_[j], o[i][j]);
  }

  const float sch = SCALE[h];
  #pragma unroll
  for (int i = 0; i < 4; ++i) {
    const int t = t0 + ty * 4 + i;
    const float fac = sch / sqrtf((float)(t + 1));
    half4h hv, lv;
    #pragma unroll
    for (int j = 0; j < 4; ++j) {
      float v = o[i][j] * fac;
      half_t hx = (half_t)v;
      hv[j] = hx; lv[j] = (half_t)((v - (float)hx) * 2048.f);
    }
    *(half4h*)&ATTHI[(size_t)(b * Tt + t) * Dd + h * 64 + tx * 4] = hv;
    *(half4h*)&ATTLO[(size_t)(b * Tt + t) * Dd + h * 64 + tx * 4] = lv;
  }
}

// ---------------------------------------------------------------------------
extern "C" void kernel_launch(void* const* d_in, const int* in_sizes, int n_in,
                              void* d_out, int out_size, void* d_ws, size_t ws_size,
                              hipStream_t stream) {
  const float* x   = (const float*)d_in[0];
  const float* Wqf = (const float*)d_in[1];
  const float* bqf = (const float*)d_in[2];
  const float* Wkf = (const float*)d_in[3];
  const float* bkf = (const float*)d_in[4];
  const float* Wqp = (const float*)d_in[5];
  const float* bqp = (const float*)d_in[6];
  const float* Wkp = (const float*)d_in[7];
  const float* bkp = (const float*)d_in[8];
  const float* Wv  = (const float*)d_in[9];
  const float* bv  = (const float*)d_in[10];
  const float* Wo  = (const float*)d_in[11];
  const float* bo  = (const float*)d_in[12];
  const float* scale = (const float*)d_in[13];

  // ws layout (56 MB): Wsplit 24 MB | qnh 8 MB | knh 8 MB | G 16 MB
  half_t* WSP = (half_t*)d_ws;                 // 6 mats x (hi 1M + lo 1M) halves
  half_t* qnh = WSP + 12582912;                // 4,194,304 halves
  half_t* knh = qnh + 4194304;
  float*  G   = (float*)(knh + 4194304);
  half_t* xhi = (half_t*)G;                    // x halves alias G: dead before
  half_t* xlo = xhi + 4194304;                 // chunk_kv writes G
  float*  vbuf = (float*)d_out;                // v lives in d_out, consumed
                                               // before the final out-gemm

  xsplit_kernel<<<dim3(2048), 256, 0, stream>>>(x, xhi, xlo);

  // mat order in WSP: 0=qf 1=qp 2=kf 3=kp 4=v 5=o
  wsplit_kernel<<<dim3(16, 16, 6), 256, 0, stream>>>(Wqf, Wqp, Wkf, Wkp, Wv, Wo, WSP);

  proj_kernel<<<dim3(Tt / 128, Hh, Bb * 2), 256, 0, stream>>>(
      xhi, xlo, WSP, bqf, bqp, bkf, bkp, qnh, knh);

  gemm_kernel<<<dim3((Bb * Tt) / 128, Dd / 64), 256, 0, stream>>>(
      xhi, xlo, WSP + (size_t)4 * 2097152, bv, vbuf);

  chunk_kv_kernel<<<dim3(NC, Hh, Bb), 256, 0, stream>>>(knh, vbuf, G);
  prefix_kernel<<<dim3(16, Hh, Bb), 256, 0, stream>>>(G);
  attn_chunk_kernel<<<dim3(NC, Hh, Bb), 256, 0, stream>>>(
      qnh, knh, vbuf, G, scale, qnh /*atthi*/, knh /*attlo*/);

  gemm_kernel<<<dim3((Bb * Tt) / 128, Dd / 64), 256, 0, stream>>>(
      qnh, knh, WSP + (size_t)5 * 2097152, bo, (float*)d_out);
}

// Round 12
// 345.115 us; speedup vs baseline: 1.2276x; 1.0986x over previous
//
#include <hip/hip_runtime.h>

// PureWaveAttention B=2,T=2048,D=1024,H=16,NW=64,HD=64 — fp32 I/O, all GEMMs
// on MFMA via 2-term fp16 split: a = hi + lo/2048 (lo stored pre-scaled x2048).
// C = hh(hi,hi) + mx(hi,lo + lo,hi)/2048. Rel err 2^-22 -> fp32-equivalent.
// Pipeline (6 launches):
//  0) xwsplit: FUSED xsplit (x->xhi/xlo, blocks 0..2047) + wsplit (W->Whi/Wlo,
//     blocks 2048..3583) — independent preprocessing, one dispatch.
//  1) projv: FUSED proj (blocks 0..1023, R8 body) + vgemm (blocks 1024..1279,
//     R8 128^2 gemm body). Independent (both read xhi/xlo/WSP only); vgemm
//     alone is grid-limited (256 blocks = 1/CU) — fused, its blocks backfill
//     CUs and co-reside with proj blocks.
//  2) chunk_kv -> G; 3) prefix -> M; 4) attn_chunk -> att (aliases qnh/knh)
//  5) outgemm: d_out = att@Wo+bo (R8 gemm kernel)
// R12: revert R11's N64 gemm (regressed 360->379; tile-geometry fragile,
// keep R8 128^2 BAR_LG) + launch fusion above. proj internals frozen at R8
// (137us; 7 variants all >=).
// ws (56 MB): Wsplit 24 | qnh 8 | knh 8 | G 16 (xhi/xlo alias G before chunk_kv)

#define Bb 2
#define Tt 2048
#define Dd 1024
#define Hh 16
#define NC 32

typedef _Float16 half_t;
typedef _Float16 half8 __attribute__((ext_vector_type(8)));
typedef _Float16 half4h __attribute__((ext_vector_type(4)));
typedef float f32x16 __attribute__((ext_vector_type(16)));

#define MFMA32(a, b, c) __builtin_amdgcn_mfma_f32_32x32x16_f16((a), (b), (c), 0, 0, 0)

// global_load_lds: per-lane global src, wave-uniform LDS base + lane*16.
#define GLL(G, L) __builtin_amdgcn_global_load_lds(                      \
    (const __attribute__((address_space(1))) void*)(G),                  \
    (__attribute__((address_space(3))) void*)(L), 16, 0, 0)

#define SCHED_FENCE() __builtin_amdgcn_sched_barrier(0)

// proj phase barrier: drain all but the 4 newest vmem ops (= this phase's
// GLLs). No sched fences (R7 lesson).
#define BARC() {                                                         \
    asm volatile("s_waitcnt vmcnt(4) lgkmcnt(0)" ::: "memory");          \
    __builtin_amdgcn_s_barrier(); }

// gemm phase barrier, LDS ordering only (vmem stays in flight).
#define BAR_LG() {                                                       \
    SCHED_FENCE();                                                       \
    asm volatile("s_waitcnt lgkmcnt(0)" ::: "memory");                   \
    __builtin_amdgcn_s_barrier();                                        \
    SCHED_FENCE(); }

// ---------------------------------------------------------------------------
// Kernel 0: FUSED xsplit + wsplit.
//  blocks 0..2047: x fp32 -> xhi, xlo fp16 (lo pre-scaled x2048)
//  blocks 2048..3583: W[k][n] fp32 -> hi[n][k], lo[n][k] fp16 per matrix m
// ---------------------------------------------------------------------------
__global__ __launch_bounds__(256) void xwsplit_kernel(
    const float* __restrict__ X,
    const float* __restrict__ W0, const float* __restrict__ W1,
    const float* __restrict__ W2, const float* __restrict__ W3,
    const float* __restrict__ W4, const float* __restrict__ W5,
    half_t* __restrict__ XHI, half_t* __restrict__ XLO,
    half_t* __restrict__ WSP)
{
  __shared__ float Ld[64][68];
  const int tid = threadIdx.x;
  const int bid = blockIdx.x;
  if (bid < 2048) {
    const size_t i = ((size_t)bid * 256 + tid) * 8;
    float4 a = *(const float4*)&X[i];
    float4 b = *(const float4*)&X[i + 4];
    const float av[8] = {a.x, a.y, a.z, a.w, b.x, b.y, b.z, b.w};
    half8 hv, lv;
    #pragma unroll
    for (int j = 0; j < 8; ++j) {
      half_t hx = (half_t)av[j];
      hv[j] = hx; lv[j] = (half_t)((av[j] - (float)hx) * 2048.f);
    }
    *(half8*)&XHI[i] = hv;
    *(half8*)&XLO[i] = lv;
    return;
  }
  const int idx = bid - 2048;
  const int m = idx >> 8;
  const float* W = (m == 0) ? W0 : (m == 1) ? W1 : (m == 2) ? W2
                 : (m == 3) ? W3 : (m == 4) ? W4 : W5;
  const int k0 = (idx & 15) * 64, n0 = ((idx >> 4) & 15) * 64;
  const int r = tid >> 2, c4 = (tid & 3) * 16;
  #pragma unroll
  for (int i = 0; i < 4; ++i)
    *(float4*)&Ld[r][c4 + i * 4] =
        *(const float4*)&W[(size_t)(k0 + r) * Dd + n0 + c4 + i * 4];
  __syncthreads();
  half_t* hi = WSP + (size_t)m * 2097152;
  half_t* lo = hi + 1048576;
  const int n = tid >> 2, kc = (tid & 3) * 16;
  half8 hv0, hv1, lv0, lv1;
  #pragma unroll
  for (int i = 0; i < 8; ++i) {
    float v0 = Ld[kc + i][n];
    half_t h0 = (half_t)v0;
    hv0[i] = h0; lv0[i] = (half_t)((v0 - (float)h0) * 2048.f);
    float v1 = Ld[kc + 8 + i][n];
    half_t h1 = (half_t)v1;
    hv1[i] = h1; lv1[i] = (half_t)((v1 - (float)h1) * 2048.f);
  }
  *(half8*)&hi[(size_t)(n0 + n) * Dd + k0 + kc]     = hv0;
  *(half8*)&hi[(size_t)(n0 + n) * Dd + k0 + kc + 8] = hv1;
  *(half8*)&lo[(size_t)(n0 + n) * Dd + k0 + kc]     = lv0;
  *(half8*)&lo[(size_t)(n0 + n) * Dd + k0 + kc + 8] = lv1;
}

// ---------------------------------------------------------------------------
// Kernel 1: FUSED proj + vgemm. One 64KB LDS union.
//  blocks 0..1023 (proj, R8 body): block = 128 t-rows x (64 F | 64 P) for
//   head h, pair p. Wave w: A rows 32w..+31 in regs; B QUAD-buffered via
//   global_load_lds (stage 2 phases ahead); BARC vmcnt(4) barriers.
//   B LDS: [4][128][64]; row = 8x16B chunks [hi 0..3|lo 4..7], chunk c at
//   phys c^(row&7); per-lane global source pre-swizzled to match.
//  blocks 1024..1279 (vgemm, R8 gemm body): 128x128 dbuf, row-per-thread
//   ds_write staging, XOR-swz, BAR_LG barriers. OUT = vbuf, W = Wv, bias bv.
// ---------------------------------------------------------------------------
__global__ __launch_bounds__(256, 2) void projv_kernel(
    const half_t* __restrict__ XHI, const half_t* __restrict__ XLO,
    const half_t* __restrict__ WSP,
    const float* __restrict__ bqf, const float* __restrict__ bqp,
    const float* __restrict__ bkf, const float* __restrict__ bkp,
    half_t* __restrict__ QNH, half_t* __restrict__ KNH,
    const float* __restrict__ BV, float* __restrict__ VOUT)
{
  __shared__ __align__(16) half_t LDSU[32768];   // 64 KB
  const int tid = threadIdx.x;
  const int bid = blockIdx.x;
  const int lane = tid & 63, w = tid >> 6;
  const int rl = lane & 31, kq = lane >> 5;
  const int sw = rl & 7;

  if (bid < 1024) {
    // ----------------------------- proj role ------------------------------
    half_t (*Bs)[128][64] = (half_t (*)[128][64])LDSU;
    const int mb = bid & 15, h = (bid >> 4) & 15;
    const int z = bid >> 8;
    const int b = z >> 1, p = z & 1;
    const int t0 = mb * 128, row0 = b * Tt + t0, col0 = h * 64;
    const half_t* WF = WSP + (size_t)(2 * p) * 2097152;    // hi; lo at +1048576
    const half_t* WP = WSP + (size_t)(2 * p + 1) * 2097152;
    const float* BF = p ? bkf : bqf;
    const float* BP = p ? bkp : bqp;
    half_t* OUTH = p ? KNH : QNH;

    f32x16 hh[4], mx[4];
    #pragma unroll
    for (int i = 0; i < 4; ++i) { hh[i] = (f32x16)(0.f); mx[i] = (f32x16)(0.f); }

    const half_t* aHi = XHI + (size_t)(row0 + 32 * w + rl) * Dd + kq * 8;
    const half_t* aLo = XLO + (size_t)(row0 + 32 * w + rl) * Dd + kq * 8;

    const int lr8 = lane >> 3;
    const int lcc = (lane & 7) ^ lr8;
    const int csel = (lcc & 3) * 8;
    const size_t loOff = (lcc >= 4) ? 1048576 : 0;
    const half_t* gb0 = WF + loOff + (size_t)(col0 + 8 * w + lr8) * Dd + csel;
    const half_t* gb1 = gb0 + 32 * Dd;
    const half_t* gb2 = WP + loOff + (size_t)(col0 + 8 * w + lr8) * Dd + csel;
    const half_t* gb3 = gb2 + 32 * Dd;

#define STAGE_PB(BI, K) {                          \
    GLL(gb0 + (K), &Bs[BI][8 * w][0]);             \
    GLL(gb1 + (K), &Bs[BI][32 + 8 * w][0]);        \
    GLL(gb2 + (K), &Bs[BI][64 + 8 * w][0]);        \
    GLL(gb3 + (K), &Bs[BI][96 + 8 * w][0]); }

#define LOADA(H0, H1, L0, L1, K) {                 \
    H0 = *(const half8*)&aHi[(K)];                 \
    H1 = *(const half8*)&aHi[(K) + 16];            \
    L0 = *(const half8*)&aLo[(K)];                 \
    L1 = *(const half8*)&aLo[(K) + 16]; }

#define KT_P(H0, H1, L0, L1, BI) {                                     \
    { const int c0 = (kq ^ sw) * 8, c1 = ((4 + kq) ^ sw) * 8;          \
      _Pragma("unroll")                                                \
      for (int tn = 0; tn < 4; ++tn) {                                 \
        half8 bh = *(const half8*)&Bs[BI][32 * tn + rl][c0];           \
        half8 bl = *(const half8*)&Bs[BI][32 * tn + rl][c1];           \
        hh[tn] = MFMA32(H0, bh, hh[tn]);                               \
        mx[tn] = MFMA32(H0, bl, mx[tn]);                               \
        mx[tn] = MFMA32(L0, bh, mx[tn]); } }                           \
    { const int c0 = (((2 + kq)) ^ sw) * 8, c1 = ((6 + kq) ^ sw) * 8;  \
      _Pragma("unroll")                                                \
      for (int tn = 0; tn < 4; ++tn) {                                 \
        half8 bh = *(const half8*)&Bs[BI][32 * tn + rl][c0];           \
        half8 bl = *(const half8*)&Bs[BI][32 * tn + rl][c1];           \
        hh[tn] = MFMA32(H1, bh, hh[tn]);                               \
        mx[tn] = MFMA32(H1, bl, mx[tn]);                               \
        mx[tn] = MFMA32(L1, bh, mx[tn]); } } }

    half8 ah0c, ah1c, al0c, al1c, ah0n, ah1n, al0n, al1n;
    STAGE_PB(0, 0)
    STAGE_PB(1, 32)
    LOADA(ah0c, ah1c, al0c, al1c, 0)
    BARC()

    #pragma unroll 1
    for (int k0 = 0; k0 < Dd; k0 += 128) {    // 4 phases (32-k each) per iter
      LOADA(ah0n, ah1n, al0n, al1n, k0 + 32)
      STAGE_PB(2, k0 + 64)
      KT_P(ah0c, ah1c, al0c, al1c, 0)
      BARC()
      LOADA(ah0c, ah1c, al0c, al1c, k0 + 64)
      STAGE_PB(3, k0 + 96)
      KT_P(ah0n, ah1n, al0n, al1n, 1)
      BARC()
      LOADA(ah0n, ah1n, al0n, al1n, k0 + 96)
      if (k0 + 128 < Dd) { STAGE_PB(0, k0 + 128) }
      KT_P(ah0c, ah1c, al0c, al1c, 2)
      BARC()
      if (k0 + 128 < Dd) { LOADA(ah0c, ah1c, al0c, al1c, k0 + 128) }
      if (k0 + 160 < Dd) { STAGE_PB(1, k0 + 160) }
      KT_P(ah0n, ah1n, al0n, al1n, 3)
      BARC()
    }
#undef STAGE_PB
#undef LOADA
#undef KT_P

    const float bf0 = BF[col0 + rl], bf1 = BF[col0 + 32 + rl];
    const float bp0 = BP[col0 + rl], bp1 = BP[col0 + 32 + rl];
    #pragma unroll
    for (int j = 0; j < 16; ++j) {
      const int rtj = (j & 3) + 8 * (j >> 2) + 4 * kq;
      const float tf = (float)(t0 + 32 * w + rtj);
      float f0 = hh[0][j] + mx[0][j] * (1.f / 2048.f) + bf0;
      float f1 = hh[1][j] + mx[1][j] * (1.f / 2048.f) + bf1;
      float p0 = hh[2][j] + mx[2][j] * (1.f / 2048.f) + bp0;
      float p1 = hh[3][j] + mx[3][j] * (1.f / 2048.f) + bp1;
      float w0 = sinf(fmaf(f0, tf, p0));
      float w1 = sinf(fmaf(f1, tf, p1));
      float ss = w0 * w0 + w1 * w1;
      ss += __shfl_xor(ss, 1); ss += __shfl_xor(ss, 2);
      ss += __shfl_xor(ss, 4); ss += __shfl_xor(ss, 8);
      ss += __shfl_xor(ss, 16);
      const float inv = 1.f / fmaxf(sqrtf(ss), 1e-12f);
      half_t* op = &OUTH[((size_t)(b * Tt) + t0 + 32 * w + rtj) * Dd + col0];
      op[rl]      = (half_t)(w0 * inv);
      op[32 + rl] = (half_t)(w1 * inv);
    }
    return;
  }

  // ------------------------------ vgemm role ------------------------------
  {
    half_t (*AsG)[128][64] = (half_t (*)[128][64])LDSU;
    half_t (*BsG)[128][64] = (half_t (*)[128][64])(LDSU + 16384);
    const half_t* WHI = WSP + (size_t)4 * 2097152;
    const int g = bid - 1024;
    const int m0 = (g & 31) * 128, n0 = (g >> 5) * 128;

    f32x16 hh[4], mx[4];
    #pragma unroll
    for (int i = 0; i < 4; ++i) { hh[i] = (f32x16)(0.f); mx[i] = (f32x16)(0.f); }

    const int r = tid & 127, isB = tid >> 7;
    const int swr = r & 7;
    const half_t* srcHi = isB ? &WHI[(size_t)(n0 + r) * Dd]
                              : &XHI[(size_t)(m0 + r) * Dd];
    const half_t* srcLo = isB ? &WHI[1048576 + (size_t)(n0 + r) * Dd]
                              : &XLO[(size_t)(m0 + r) * Dd];
    half_t* dstRow = isB ? &BsG[0][r][0] : &AsG[0][r][0];
    const int pc0 = (0 ^ swr) * 8, pc1 = (1 ^ swr) * 8;
    const int pc2 = (2 ^ swr) * 8, pc3 = (3 ^ swr) * 8;
    const int pc4 = (4 ^ swr) * 8, pc5 = (5 ^ swr) * 8;
    const int pc6 = (6 ^ swr) * 8, pc7 = (7 ^ swr) * 8;

    half8 rg0, rg1, rg2, rg3, rg4, rg5, rg6, rg7;

#define G_LOADREGS(K)                                                          \
  rg0 = *(const half8*)&srcHi[(K)];      rg1 = *(const half8*)&srcHi[(K) + 8]; \
  rg2 = *(const half8*)&srcHi[(K) + 16]; rg3 = *(const half8*)&srcHi[(K) + 24];\
  rg4 = *(const half8*)&srcLo[(K)];      rg5 = *(const half8*)&srcLo[(K) + 8]; \
  rg6 = *(const half8*)&srcLo[(K) + 16]; rg7 = *(const half8*)&srcLo[(K) + 24];

#define G_WRITE(BI) {                                                     \
  half_t* d_ = dstRow + (BI) * 8192;                                      \
  *(half8*)&d_[pc0] = rg0; *(half8*)&d_[pc1] = rg1;                       \
  *(half8*)&d_[pc2] = rg2; *(half8*)&d_[pc3] = rg3;                       \
  *(half8*)&d_[pc4] = rg4; *(half8*)&d_[pc5] = rg5;                       \
  *(half8*)&d_[pc6] = rg6; *(half8*)&d_[pc7] = rg7; }

#define G_KT(BI)                                                          \
  _Pragma("unroll")                                                       \
  for (int ks = 0; ks < 2; ++ks) {                                        \
    half8 ahi = *(const half8*)&AsG[BI][32 * w + rl][((2 * ks + kq) ^ sw) * 8];       \
    half8 alo = *(const half8*)&AsG[BI][32 * w + rl][((4 + 2 * ks + kq) ^ sw) * 8];   \
    _Pragma("unroll")                                                     \
    for (int tn = 0; tn < 4; ++tn) {                                      \
      half8 bhi = *(const half8*)&BsG[BI][32 * tn + rl][((2 * ks + kq) ^ sw) * 8];    \
      half8 blo = *(const half8*)&BsG[BI][32 * tn + rl][((4 + 2 * ks + kq) ^ sw) * 8];\
      hh[tn] = MFMA32(ahi, bhi, hh[tn]);                                  \
      mx[tn] = MFMA32(ahi, blo, mx[tn]);                                  \
      mx[tn] = MFMA32(alo, bhi, mx[tn]);                                  \
    }                                                                     \
  }

    G_LOADREGS(0)
    G_WRITE(0)
    G_LOADREGS(32)
    BAR_LG()

    #pragma unroll 1
    for (int k0 = 0; k0 < Dd; k0 += 64) {
      G_KT(0)
      G_WRITE(1)
      if (k0 + 64 < Dd) { G_LOADREGS(k0 + 64) }
      BAR_LG()
      G_KT(1)
      if (k0 + 64 < Dd) { G_WRITE(0) }
      if (k0 + 96 < Dd) { G_LOADREGS(k0 + 96) }
      BAR_LG()
    }
#undef G_LOADREGS
#undef G_WRITE
#undef G_KT

    const float bb0 = BV[n0 + rl],      bb1 = BV[n0 + 32 + rl];
    const float bb2 = BV[n0 + 64 + rl], bb3 = BV[n0 + 96 + rl];
    #pragma unroll
    for (int j = 0; j < 16; ++j) {
      const int rtj = (j & 3) + 8 * (j >> 2) + 4 * kq;
      float* orow = &VOUT[(size_t)(m0 + 32 * w + rtj) * Dd + n0];
      orow[rl]      = hh[0][j] + mx[0][j] * (1.f / 2048.f) + bb0;
      orow[32 + rl] = hh[1][j] + mx[1][j] * (1.f / 2048.f) + bb1;
      orow[64 + rl] = hh[2][j] + mx[2][j] * (1.f / 2048.f) + bb2;
      orow[96 + rl] = hh[3][j] + mx[3][j] * (1.f / 2048.f) + bb3;
    }
  }
}

// ---------------------------------------------------------------------------
// Kernel 5: GEMM OUT[4096,1024] = A@W + bias (outgemm). R8/R7 128x128 dbuf,
// row-per-thread ds_write staging, XOR-swz, BAR_LG barriers.
// ---------------------------------------------------------------------------
__global__ __launch_bounds__(256, 2) void gemm_kernel(
    const half_t* __restrict__ AHI, const half_t* __restrict__ ALO,
    const half_t* __restrict__ WHI,
    const float* __restrict__ BIAS, float* __restrict__ OUT)
{
  __shared__ __align__(16) half_t As[2][128][64];
  __shared__ __align__(16) half_t Bs[2][128][64];
  const int tid = threadIdx.x;
  const int m0 = blockIdx.x * 128, n0 = blockIdx.y * 128;

  f32x16 hh[4], mx[4];
  #pragma unroll
  for (int i = 0; i < 4; ++i) { hh[i] = (f32x16)(0.f); mx[i] = (f32x16)(0.f); }

  const int lane = tid & 63, w = tid >> 6;
  const int rl = lane & 31, kq = lane >> 5;
  const int sw = rl & 7;

  const int r = tid & 127, isB = tid >> 7;
  const int swr = r & 7;
  const half_t* srcHi = isB ? &WHI[(size_t)(n0 + r) * Dd]
                            : &AHI[(size_t)(m0 + r) * Dd];
  const half_t* srcLo = isB ? &WHI[1048576 + (size_t)(n0 + r) * Dd]
                            : &ALO[(size_t)(m0 + r) * Dd];
  half_t* dstRow = isB ? &Bs[0][r][0] : &As[0][r][0];
  const int pc0 = (0 ^ swr) * 8, pc1 = (1 ^ swr) * 8;
  const int pc2 = (2 ^ swr) * 8, pc3 = (3 ^ swr) * 8;
  const int pc4 = (4 ^ swr) * 8, pc5 = (5 ^ swr) * 8;
  const int pc6 = (6 ^ swr) * 8, pc7 = (7 ^ swr) * 8;

  half8 rg0, rg1, rg2, rg3, rg4, rg5, rg6, rg7;

#define G_LOADREGS(K)                                                          \
  rg0 = *(const half8*)&srcHi[(K)];      rg1 = *(const half8*)&srcHi[(K) + 8]; \
  rg2 = *(const half8*)&srcHi[(K) + 16]; rg3 = *(const half8*)&srcHi[(K) + 24];\
  rg4 = *(const half8*)&srcLo[(K)];      rg5 = *(const half8*)&srcLo[(K) + 8]; \
  rg6 = *(const half8*)&srcLo[(K) + 16]; rg7 = *(const half8*)&srcLo[(K) + 24];

#define G_WRITE(BI) {                                                     \
  half_t* d_ = dstRow + (BI) * 8192;                                      \
  *(half8*)&d_[pc0] = rg0; *(half8*)&d_[pc1] = rg1;                       \
  *(half8*)&d_[pc2] = rg2; *(half8*)&d_[pc3] = rg3;                       \
  *(half8*)&d_[pc4] = rg4; *(half8*)&d_[pc5] = rg5;                       \
  *(half8*)&d_[pc6] = rg6; *(half8*)&d_[pc7] = rg7; }

#define G_KT(BI)                                                          \
  _Pragma("unroll")                                                       \
  for (int ks = 0; ks < 2; ++ks) {                                        \
    half8 ahi = *(const half8*)&As[BI][32 * w + rl][((2 * ks + kq) ^ sw) * 8];       \
    half8 alo = *(const half8*)&As[BI][32 * w + rl][((4 + 2 * ks + kq) ^ sw) * 8];   \
    _Pragma("unroll")                                                     \
    for (int tn = 0; tn < 4; ++tn) {                                      \
      half8 bhi = *(const half8*)&Bs[BI][32 * tn + rl][((2 * ks + kq) ^ sw) * 8];    \
      half8 blo = *(const half8*)&Bs[BI][32 * tn + rl][((4 + 2 * ks + kq) ^ sw) * 8];\
      hh[tn] = MFMA32(ahi, bhi, hh[tn]);                                  \
      mx[tn] = MFMA32(ahi, blo, mx[tn]);                                  \
      mx[tn] = MFMA32(alo, bhi, mx[tn]);                                  \
    }                                                                     \
  }

  G_LOADREGS(0)
  G_WRITE(0)
  G_LOADREGS(32)
  BAR_LG()

  #pragma unroll 1
  for (int k0 = 0; k0 < Dd; k0 += 64) {
    G_KT(0)
    G_WRITE(1)
    if (k0 + 64 < Dd) { G_LOADREGS(k0 + 64) }
    BAR_LG()
    G_KT(1)
    if (k0 + 64 < Dd) { G_WRITE(0) }
    if (k0 + 96 < Dd) { G_LOADREGS(k0 + 96) }
    BAR_LG()
  }
#undef G_LOADREGS
#undef G_WRITE
#undef G_KT

  const float bb0 = BIAS[n0 + rl],      bb1 = BIAS[n0 + 32 + rl];
  const float bb2 = BIAS[n0 + 64 + rl], bb3 = BIAS[n0 + 96 + rl];
  #pragma unroll
  for (int j = 0; j < 16; ++j) {
    const int rtj = (j & 3) + 8 * (j >> 2) + 4 * kq;
    float* orow = &OUT[(size_t)(m0 + 32 * w + rtj) * Dd + n0];
    orow[rl]      = hh[0][j] + mx[0][j] * (1.f / 2048.f) + bb0;
    orow[32 + rl] = hh[1][j] + mx[1][j] * (1.f / 2048.f) + bb1;
    orow[64 + rl] = hh[2][j] + mx[2][j] * (1.f / 2048.f) + bb2;
    orow[96 + rl] = hh[3][j] + mx[3][j] * (1.f / 2048.f) + bb3;
  }
}

// ---------------------------------------------------------------------------
// Kernel 2: G_c[w][d] = sum_{s in c} K[s][w]*V[s][d]. K from fp16, V fp32.
// ---------------------------------------------------------------------------
__global__ __launch_bounds__(256) void chunk_kv_kernel(
    const half_t* __restrict__ KNH, const float* __restrict__ V,
    float* __restrict__ G)
{
  __shared__ float Ks[64][64];
  __shared__ float Vs[64][64];
  const int tid = threadIdx.x;
  const int c = blockIdx.x, h = blockIdx.y, b = blockIdx.z;
  const int s0 = c * 64;
  const int lr = tid >> 2, lc = (tid & 3) * 16;
  {
    const half_t* krow = &KNH[(size_t)(b * Tt + s0 + lr) * Dd + h * 64 + lc];
    half8 ka = *(const half8*)&krow[0];
    half8 kb = *(const half8*)&krow[8];
    #pragma unroll
    for (int i = 0; i < 8; ++i) {
      Ks[lr][lc + i] = (float)ka[i];
      Ks[lr][lc + 8 + i] = (float)kb[i];
    }
    const float* vrow = &V[(size_t)(b * Tt + s0 + lr) * Dd + h * 64 + lc];
    #pragma unroll
    for (int i = 0; i < 4; ++i)
      *(float4*)&Vs[lr][lc + i * 4] = *(const float4*)&vrow[i * 4];
  }
  __syncthreads();

  const int ty = tid >> 4, tx = tid & 15;
  float g[4][4] = {{0.f}};
  #pragma unroll 4
  for (int s = 0; s < 64; ++s) {
    float4 kv = *(const float4*)&Ks[s][ty * 4];
    float4 vv = *(const float4*)&Vs[s][tx * 4];
    const float* k_ = (const float*)&kv;
    const float* v_ = (const float*)&vv;
    #pragma unroll
    for (int i = 0; i < 4; ++i)
      #pragma unroll
      for (int j = 0; j < 4; ++j)
        g[i][j] = fmaf(k_[i], v_[j], g[i][j]);
  }
  float* Gp = G + (((size_t)(b * Hh + h) * NC + c) << 12);
  #pragma unroll
  for (int i = 0; i < 4; ++i)
    *(float4*)&Gp[(ty * 4 + i) * 64 + tx * 4] =
        make_float4(g[i][0], g[i][1], g[i][2], g[i][3]);
}

// ---------------------------------------------------------------------------
// Kernel 3: in-place exclusive prefix over NC chunk matrices per (b,h).
// 512 blocks; thread = 1 float, fully coalesced.
// ---------------------------------------------------------------------------
__global__ __launch_bounds__(256) void prefix_kernel(float* __restrict__ G)
{
  const int seg = blockIdx.x, h = blockIdx.y, b = blockIdx.z;
  float* base = G + (((size_t)(b * Hh + h) * NC) << 12) + seg * 256 + threadIdx.x;
  float acc = 0.f;
  #pragma unroll 4
  for (int c = 0; c < NC; ++c) {
    float* p = base + ((size_t)c << 12);
    const float g = *p;
    *p = acc;
    acc += g;
  }
}

// ---------------------------------------------------------------------------
// Kernel 4: O_c = (Q_c M_c + tril(Q_c K_c^T) V_c) * scale/sqrt(t+1).
// Q,K from fp16; out split to fp16 hi/lo (lo x2048), aliasing qnh/knh.
// ---------------------------------------------------------------------------
__global__ __launch_bounds__(256) void attn_chunk_kernel(
    const half_t* __restrict__ QNH, const half_t* __restrict__ KNH,
    const float* __restrict__ V, const float* __restrict__ M,
    const float* __restrict__ SCALE,
    half_t* __restrict__ ATTHI, half_t* __restrict__ ATTLO)
{
  __shared__ float Qt[64][68];
  __shared__ float Kt[64][68];
  __shared__ float SM[64][68];
  __shared__ float Vs[64][64];
  const int tid = threadIdx.x;
  const int c = blockIdx.x, h = blockIdx.y, b = blockIdx.z;
  const int t0 = c * 64;
  const int lr = tid >> 2, lc = (tid & 3) * 16;
  {
    const half_t* qrow = &QNH[(size_t)(b * Tt + t0 + lr) * Dd + h * 64 + lc];
    const half_t* krow = &KNH[(size_t)(b * Tt + t0 + lr) * Dd + h * 64 + lc];
    half8 qa = *(const half8*)&qrow[0];
    half8 qb = *(const half8*)&qrow[8];
    half8 ka = *(const half8*)&krow[0];
    half8 kb = *(const half8*)&krow[8];
    #pragma unroll
    for (int i = 0; i < 8; ++i) {
      Qt[lc + i][lr] = (float)qa[i];     Qt[lc + 8 + i][lr] = (float)qb[i];
      Kt[lc + i][lr] = (float)ka[i];     Kt[lc + 8 + i][lr] = (float)kb[i];
    }
    const float* vrow = &V[(size_t)(b * Tt + t0 + lr) * Dd + h * 64 + lc];
    const float* mrow = &M[(((size_t)(b * Hh + h) * NC + c) << 12) + lr * 64 + lc];
    #pragma unroll
    for (int i = 0; i < 4; ++i) {
      *(float4*)&Vs[lr][lc + i * 4] = *(const float4*)&vrow[i * 4];
      *(float4*)&SM[lr][lc + i * 4] = *(const float4*)&mrow[i * 4];
    }
  }
  __syncthreads();

  const int ty = tid >> 4, tx = tid & 15;
  float o[4][4] = {{0.f}};
  float sc[4][4] = {{0.f}};

  #pragma unroll 4
  for (int w = 0; w < 64; ++w) {
    float4 qv = *(const float4*)&Qt[w][ty * 4];
    float4 mv = *(const float4*)&SM[w][tx * 4];
    float4 kv = *(const float4*)&Kt[w][tx * 4];
    const float* q_ = (const float*)&qv;
    const float* m_ = (const float*)&mv;
    const float* k_ = (const float*)&kv;
    #pragma unroll
    for (int i = 0; i < 4; ++i) {
      float qq = q_[i];
      #pragma unroll
      for (int j = 0; j < 4; ++j) {
        o[i][j]  = fmaf(qq, m_[j], o[i][j]);
        sc[i][j] = fmaf(qq, k_[j], sc[i][j]);
      }
    }
  }
  __syncthreads();

  #pragma unroll
  for (int i = 0; i < 4; ++i) {
    const int lt = ty * 4 + i;
    #pragma unroll
    for (int j = 0; j < 4; ++j) {
      const int ls = tx * 4 + j;
      SM[ls][lt] = (ls <= lt) ? sc[i][j] : 0.f;
    }
  }
  __syncthreads();

  #pragma unroll 4
  for (int s = 0; s < 64; ++s) {
    float4 sv = *(const float4*)&SM[s][ty * 4];
    float4 vv = *(const float4*)&Vs[s][tx * 4];
    const float* s_ = (const float*)&sv;
    const float* v_ = (const float*)&vv;
    #pragma unroll
    for (int i = 0; i < 4; ++i)
      #pragma unroll
      for (int j = 0; j < 4; ++j)
        o[i][j] = fmaf(s_[i], v_[j], o[i][j]);
  }

  const float sch = SCALE[h];
  #pragma unroll
  for (int i = 0; i < 4; ++i) {
    const int t = t0 + ty * 4 + i;
    const float fac = sch / sqrtf((float)(t + 1));
    half4h hv, lv;
    #pragma unroll
    for (int j = 0; j < 4; ++j) {
      float v = o[i][j] * fac;
      half_t hx = (half_t)v;
      hv[j] = hx; lv[j] = (half_t)((v - (float)hx) * 2048.f);
    }
    *(half4h*)&ATTHI[(size_t)(b * Tt + t) * Dd + h * 64 + tx * 4] = hv;
    *(half4h*)&ATTLO[(size_t)(b * Tt + t) * Dd + h * 64 + tx * 4] = lv;
  }
}

// ---------------------------------------------------------------------------
extern "C" void kernel_launch(void* const* d_in, const int* in_sizes, int n_in,
                              void* d_out, int out_size, void* d_ws, size_t ws_size,
                              hipStream_t stream) {
  const float* x   = (const float*)d_in[0];
  const float* Wqf = (const float*)d_in[1];
  const float* bqf = (const float*)d_in[2];
  const float* Wkf = (const float*)d_in[3];
  const float* bkf = (const float*)d_in[4];
  const float* Wqp = (const float*)d_in[5];
  const float* bqp = (const float*)d_in[6];
  const float* Wkp = (const float*)d_in[7];
  const float* bkp = (const float*)d_in[8];
  const float* Wv  = (const float*)d_in[9];
  const float* bv  = (const float*)d_in[10];
  const float* Wo  = (const float*)d_in[11];
  const float* bo  = (const float*)d_in[12];
  const float* scale = (const float*)d_in[13];

  // ws layout (56 MB): Wsplit 24 MB | qnh 8 MB | knh 8 MB | G 16 MB
  half_t* WSP = (half_t*)d_ws;                 // 6 mats x (hi 1M + lo 1M) halves
  half_t* qnh = WSP + 12582912;                // 4,194,304 halves
  half_t* knh = qnh + 4194304;
  float*  G   = (float*)(knh + 4194304);
  half_t* xhi = (half_t*)G;                    // x halves alias G: dead before
  half_t* xlo = xhi + 4194304;                 // chunk_kv writes G
  float*  vbuf = (float*)d_out;                // v lives in d_out, consumed
                                               // before the final out-gemm

  // mat order in WSP: 0=qf 1=qp 2=kf 3=kp 4=v 5=o
  xwsplit_kernel<<<dim3(2048 + 1536), 256, 0, stream>>>(
      x, Wqf, Wqp, Wkf, Wkp, Wv, Wo, xhi, xlo, WSP);

  projv_kernel<<<dim3(1024 + 256), 256, 0, stream>>>(
      xhi, xlo, WSP, bqf, bqp, bkf, bkp, qnh, knh, bv, vbuf);

  chunk_kv_kernel<<<dim3(NC, Hh, Bb), 256, 0, stream>>>(knh, vbuf, G);
  prefix_kernel<<<dim3(16, Hh, Bb), 256, 0, stream>>>(G);
  attn_chunk_kernel<<<dim3(NC, Hh, Bb), 256, 0, stream>>>(
      qnh, knh, vbuf, G, scale, qnh /*atthi*/, knh /*attlo*/);

  gemm_kernel<<<dim3((Bb * Tt) / 128, Dd / 128), 256, 0, stream>>>(
      qnh, knh, WSP + (size_t)5 * 2097152, bo, (float*)d_out);
}

// Round 13
// 333.006 us; speedup vs baseline: 1.2722x; 1.0364x over previous
//
#include <hip/hip_runtime.h>

// PureWaveAttention B=2,T=2048,D=1024,H=16,NW=64,HD=64 — fp32 I/O, all GEMMs
// on MFMA via 2-term fp16 split: a = hi + lo/2048 (lo stored pre-scaled x2048).
// C = hh(hi,hi) + mx(hi,lo + lo,hi)/2048. Rel err 2^-22 -> fp32-equivalent.
// Pipeline (6 launches):
//  0) xwsplit: FUSED xsplit + wsplit (R12)
//  1) projv: FUSED proj (R8 body) + vgemm (R8 gemm body) (R12)
//  2) chunk_kv -> G; 3) prefix -> M; 4) attn_chunk -> att (aliases qnh/knh)
//  5) outgemm: d_out = att@Wo+bo (R8 gemm kernel)
// R13: chunk_kv + attn_chunk moved from scalar VALU to MFMA32 (last scalar
// compute; G10). chunk_kv: LDS K^T fp16 + V^T split, 8 MFMA/wave. attn:
// Q/K frags direct from global, S=QK^T (4 pure-fp16 MFMA), mask+split S->LDS,
// one barrier, O = Q@M^T + S@V^T (20 split MFMAs). Same math/mask/scale;
// added error only fp16-split class (2^-22), same as main gemms.
// All LDS tiles [64][64] halves, chunk c of row r at phys c^(r&7) (proj's
// proven swizzle); frag reads/writes use row&7 == rl&7 invariant.
// ws (56 MB): Wsplit 24 | qnh 8 | knh 8 | G 16 (xhi/xlo alias G before chunk_kv)

#define Bb 2
#define Tt 2048
#define Dd 1024
#define Hh 16
#define NC 32

typedef _Float16 half_t;
typedef _Float16 half8 __attribute__((ext_vector_type(8)));
typedef _Float16 half4h __attribute__((ext_vector_type(4)));
typedef float f32x16 __attribute__((ext_vector_type(16)));

#define MFMA32(a, b, c) __builtin_amdgcn_mfma_f32_32x32x16_f16((a), (b), (c), 0, 0, 0)

// global_load_lds: per-lane global src, wave-uniform LDS base + lane*16.
#define GLL(G, L) __builtin_amdgcn_global_load_lds(                      \
    (const __attribute__((address_space(1))) void*)(G),                  \
    (__attribute__((address_space(3))) void*)(L), 16, 0, 0)

#define SCHED_FENCE() __builtin_amdgcn_sched_barrier(0)

// proj phase barrier: drain all but the 4 newest vmem ops (= this phase's
// GLLs). No sched fences (R7 lesson).
#define BARC() {                                                         \
    asm volatile("s_waitcnt vmcnt(4) lgkmcnt(0)" ::: "memory");          \
    __builtin_amdgcn_s_barrier(); }

// gemm phase barrier, LDS ordering only (vmem stays in flight).
#define BAR_LG() {                                                       \
    SCHED_FENCE();                                                       \
    asm volatile("s_waitcnt lgkmcnt(0)" ::: "memory");                   \
    __builtin_amdgcn_s_barrier();                                        \
    SCHED_FENCE(); }

// ---------------------------------------------------------------------------
// Kernel 0: FUSED xsplit + wsplit.
// ---------------------------------------------------------------------------
__global__ __launch_bounds__(256) void xwsplit_kernel(
    const float* __restrict__ X,
    const float* __restrict__ W0, const float* __restrict__ W1,
    const float* __restrict__ W2, const float* __restrict__ W3,
    const float* __restrict__ W4, const float* __restrict__ W5,
    half_t* __restrict__ XHI, half_t* __restrict__ XLO,
    half_t* __restrict__ WSP)
{
  __shared__ float Ld[64][68];
  const int tid = threadIdx.x;
  const int bid = blockIdx.x;
  if (bid < 2048) {
    const size_t i = ((size_t)bid * 256 + tid) * 8;
    float4 a = *(const float4*)&X[i];
    float4 b = *(const float4*)&X[i + 4];
    const float av[8] = {a.x, a.y, a.z, a.w, b.x, b.y, b.z, b.w};
    half8 hv, lv;
    #pragma unroll
    for (int j = 0; j < 8; ++j) {
      half_t hx = (half_t)av[j];
      hv[j] = hx; lv[j] = (half_t)((av[j] - (float)hx) * 2048.f);
    }
    *(half8*)&XHI[i] = hv;
    *(half8*)&XLO[i] = lv;
    return;
  }
  const int idx = bid - 2048;
  const int m = idx >> 8;
  const float* W = (m == 0) ? W0 : (m == 1) ? W1 : (m == 2) ? W2
                 : (m == 3) ? W3 : (m == 4) ? W4 : W5;
  const int k0 = (idx & 15) * 64, n0 = ((idx >> 4) & 15) * 64;
  const int r = tid >> 2, c4 = (tid & 3) * 16;
  #pragma unroll
  for (int i = 0; i < 4; ++i)
    *(float4*)&Ld[r][c4 + i * 4] =
        *(const float4*)&W[(size_t)(k0 + r) * Dd + n0 + c4 + i * 4];
  __syncthreads();
  half_t* hi = WSP + (size_t)m * 2097152;
  half_t* lo = hi + 1048576;
  const int n = tid >> 2, kc = (tid & 3) * 16;
  half8 hv0, hv1, lv0, lv1;
  #pragma unroll
  for (int i = 0; i < 8; ++i) {
    float v0 = Ld[kc + i][n];
    half_t h0 = (half_t)v0;
    hv0[i] = h0; lv0[i] = (half_t)((v0 - (float)h0) * 2048.f);
    float v1 = Ld[kc + 8 + i][n];
    half_t h1 = (half_t)v1;
    hv1[i] = h1; lv1[i] = (half_t)((v1 - (float)h1) * 2048.f);
  }
  *(half8*)&hi[(size_t)(n0 + n) * Dd + k0 + kc]     = hv0;
  *(half8*)&hi[(size_t)(n0 + n) * Dd + k0 + kc + 8] = hv1;
  *(half8*)&lo[(size_t)(n0 + n) * Dd + k0 + kc]     = lv0;
  *(half8*)&lo[(size_t)(n0 + n) * Dd + k0 + kc + 8] = lv1;
}

// ---------------------------------------------------------------------------
// Kernel 1: FUSED proj + vgemm (R12, frozen).
// ---------------------------------------------------------------------------
__global__ __launch_bounds__(256, 2) void projv_kernel(
    const half_t* __restrict__ XHI, const half_t* __restrict__ XLO,
    const half_t* __restrict__ WSP,
    const float* __restrict__ bqf, const float* __restrict__ bqp,
    const float* __restrict__ bkf, const float* __restrict__ bkp,
    half_t* __restrict__ QNH, half_t* __restrict__ KNH,
    const float* __restrict__ BV, float* __restrict__ VOUT)
{
  __shared__ __align__(16) half_t LDSU[32768];   // 64 KB
  const int tid = threadIdx.x;
  const int bid = blockIdx.x;
  const int lane = tid & 63, w = tid >> 6;
  const int rl = lane & 31, kq = lane >> 5;
  const int sw = rl & 7;

  if (bid < 1024) {
    // ----------------------------- proj role ------------------------------
    half_t (*Bs)[128][64] = (half_t (*)[128][64])LDSU;
    const int mb = bid & 15, h = (bid >> 4) & 15;
    const int z = bid >> 8;
    const int b = z >> 1, p = z & 1;
    const int t0 = mb * 128, row0 = b * Tt + t0, col0 = h * 64;
    const half_t* WF = WSP + (size_t)(2 * p) * 2097152;    // hi; lo at +1048576
    const half_t* WP = WSP + (size_t)(2 * p + 1) * 2097152;
    const float* BF = p ? bkf : bqf;
    const float* BP = p ? bkp : bqp;
    half_t* OUTH = p ? KNH : QNH;

    f32x16 hh[4], mx[4];
    #pragma unroll
    for (int i = 0; i < 4; ++i) { hh[i] = (f32x16)(0.f); mx[i] = (f32x16)(0.f); }

    const half_t* aHi = XHI + (size_t)(row0 + 32 * w + rl) * Dd + kq * 8;
    const half_t* aLo = XLO + (size_t)(row0 + 32 * w + rl) * Dd + kq * 8;

    const int lr8 = lane >> 3;
    const int lcc = (lane & 7) ^ lr8;
    const int csel = (lcc & 3) * 8;
    const size_t loOff = (lcc >= 4) ? 1048576 : 0;
    const half_t* gb0 = WF + loOff + (size_t)(col0 + 8 * w + lr8) * Dd + csel;
    const half_t* gb1 = gb0 + 32 * Dd;
    const half_t* gb2 = WP + loOff + (size_t)(col0 + 8 * w + lr8) * Dd + csel;
    const half_t* gb3 = gb2 + 32 * Dd;

#define STAGE_PB(BI, K) {                          \
    GLL(gb0 + (K), &Bs[BI][8 * w][0]);             \
    GLL(gb1 + (K), &Bs[BI][32 + 8 * w][0]);        \
    GLL(gb2 + (K), &Bs[BI][64 + 8 * w][0]);        \
    GLL(gb3 + (K), &Bs[BI][96 + 8 * w][0]); }

#define LOADA(H0, H1, L0, L1, K) {                 \
    H0 = *(const half8*)&aHi[(K)];                 \
    H1 = *(const half8*)&aHi[(K) + 16];            \
    L0 = *(const half8*)&aLo[(K)];                 \
    L1 = *(const half8*)&aLo[(K) + 16]; }

#define KT_P(H0, H1, L0, L1, BI) {                                     \
    { const int c0 = (kq ^ sw) * 8, c1 = ((4 + kq) ^ sw) * 8;          \
      _Pragma("unroll")                                                \
      for (int tn = 0; tn < 4; ++tn) {                                 \
        half8 bh = *(const half8*)&Bs[BI][32 * tn + rl][c0];           \
        half8 bl = *(const half8*)&Bs[BI][32 * tn + rl][c1];           \
        hh[tn] = MFMA32(H0, bh, hh[tn]);                               \
        mx[tn] = MFMA32(H0, bl, mx[tn]);                               \
        mx[tn] = MFMA32(L0, bh, mx[tn]); } }                           \
    { const int c0 = (((2 + kq)) ^ sw) * 8, c1 = ((6 + kq) ^ sw) * 8;  \
      _Pragma("unroll")                                                \
      for (int tn = 0; tn < 4; ++tn) {                                 \
        half8 bh = *(const half8*)&Bs[BI][32 * tn + rl][c0];           \
        half8 bl = *(const half8*)&Bs[BI][32 * tn + rl][c1];           \
        hh[tn] = MFMA32(H1, bh, hh[tn]);                               \
        mx[tn] = MFMA32(H1, bl, mx[tn]);                               \
        mx[tn] = MFMA32(L1, bh, mx[tn]); } } }

    half8 ah0c, ah1c, al0c, al1c, ah0n, ah1n, al0n, al1n;
    STAGE_PB(0, 0)
    STAGE_PB(1, 32)
    LOADA(ah0c, ah1c, al0c, al1c, 0)
    BARC()

    #pragma unroll 1
    for (int k0 = 0; k0 < Dd; k0 += 128) {    // 4 phases (32-k each) per iter
      LOADA(ah0n, ah1n, al0n, al1n, k0 + 32)
      STAGE_PB(2, k0 + 64)
      KT_P(ah0c, ah1c, al0c, al1c, 0)
      BARC()
      LOADA(ah0c, ah1c, al0c, al1c, k0 + 64)
      STAGE_PB(3, k0 + 96)
      KT_P(ah0n, ah1n, al0n, al1n, 1)
      BARC()
      LOADA(ah0n, ah1n, al0n, al1n, k0 + 96)
      if (k0 + 128 < Dd) { STAGE_PB(0, k0 + 128) }
      KT_P(ah0c, ah1c, al0c, al1c, 2)
      BARC()
      if (k0 + 128 < Dd) { LOADA(ah0c, ah1c, al0c, al1c, k0 + 128) }
      if (k0 + 160 < Dd) { STAGE_PB(1, k0 + 160) }
      KT_P(ah0n, ah1n, al0n, al1n, 3)
      BARC()
    }
#undef STAGE_PB
#undef LOADA
#undef KT_P

    const float bf0 = BF[col0 + rl], bf1 = BF[col0 + 32 + rl];
    const float bp0 = BP[col0 + rl], bp1 = BP[col0 + 32 + rl];
    #pragma unroll
    for (int j = 0; j < 16; ++j) {
      const int rtj = (j & 3) + 8 * (j >> 2) + 4 * kq;
      const float tf = (float)(t0 + 32 * w + rtj);
      float f0 = hh[0][j] + mx[0][j] * (1.f / 2048.f) + bf0;
      float f1 = hh[1][j] + mx[1][j] * (1.f / 2048.f) + bf1;
      float p0 = hh[2][j] + mx[2][j] * (1.f / 2048.f) + bp0;
      float p1 = hh[3][j] + mx[3][j] * (1.f / 2048.f) + bp1;
      float w0 = sinf(fmaf(f0, tf, p0));
      float w1 = sinf(fmaf(f1, tf, p1));
      float ss = w0 * w0 + w1 * w1;
      ss += __shfl_xor(ss, 1); ss += __shfl_xor(ss, 2);
      ss += __shfl_xor(ss, 4); ss += __shfl_xor(ss, 8);
      ss += __shfl_xor(ss, 16);
      const float inv = 1.f / fmaxf(sqrtf(ss), 1e-12f);
      half_t* op = &OUTH[((size_t)(b * Tt) + t0 + 32 * w + rtj) * Dd + col0];
      op[rl]      = (half_t)(w0 * inv);
      op[32 + rl] = (half_t)(w1 * inv);
    }
    return;
  }

  // ------------------------------ vgemm role ------------------------------
  {
    half_t (*AsG)[128][64] = (half_t (*)[128][64])LDSU;
    half_t (*BsG)[128][64] = (half_t (*)[128][64])(LDSU + 16384);
    const half_t* WHI = WSP + (size_t)4 * 2097152;
    const int g = bid - 1024;
    const int m0 = (g & 31) * 128, n0 = (g >> 5) * 128;

    f32x16 hh[4], mx[4];
    #pragma unroll
    for (int i = 0; i < 4; ++i) { hh[i] = (f32x16)(0.f); mx[i] = (f32x16)(0.f); }

    const int r = tid & 127, isB = tid >> 7;
    const int swr = r & 7;
    const half_t* srcHi = isB ? &WHI[(size_t)(n0 + r) * Dd]
                              : &XHI[(size_t)(m0 + r) * Dd];
    const half_t* srcLo = isB ? &WHI[1048576 + (size_t)(n0 + r) * Dd]
                              : &XLO[(size_t)(m0 + r) * Dd];
    half_t* dstRow = isB ? &BsG[0][r][0] : &AsG[0][r][0];
    const int pc0 = (0 ^ swr) * 8, pc1 = (1 ^ swr) * 8;
    const int pc2 = (2 ^ swr) * 8, pc3 = (3 ^ swr) * 8;
    const int pc4 = (4 ^ swr) * 8, pc5 = (5 ^ swr) * 8;
    const int pc6 = (6 ^ swr) * 8, pc7 = (7 ^ swr) * 8;

    half8 rg0, rg1, rg2, rg3, rg4, rg5, rg6, rg7;

#define G_LOADREGS(K)                                                          \
  rg0 = *(const half8*)&srcHi[(K)];      rg1 = *(const half8*)&srcHi[(K) + 8]; \
  rg2 = *(const half8*)&srcHi[(K) + 16]; rg3 = *(const half8*)&srcHi[(K) + 24];\
  rg4 = *(const half8*)&srcLo[(K)];      rg5 = *(const half8*)&srcLo[(K) + 8]; \
  rg6 = *(const half8*)&srcLo[(K) + 16]; rg7 = *(const half8*)&srcLo[(K) + 24];

#define G_WRITE(BI) {                                                     \
  half_t* d_ = dstRow + (BI) * 8192;                                      \
  *(half8*)&d_[pc0] = rg0; *(half8*)&d_[pc1] = rg1;                       \
  *(half8*)&d_[pc2] = rg2; *(half8*)&d_[pc3] = rg3;                       \
  *(half8*)&d_[pc4] = rg4; *(half8*)&d_[pc5] = rg5;                       \
  *(half8*)&d_[pc6] = rg6; *(half8*)&d_[pc7] = rg7; }

#define G_KT(BI)                                                          \
  _Pragma("unroll")                                                       \
  for (int ks = 0; ks < 2; ++ks) {                                        \
    half8 ahi = *(const half8*)&AsG[BI][32 * w + rl][((2 * ks + kq) ^ sw) * 8];       \
    half8 alo = *(const half8*)&AsG[BI][32 * w + rl][((4 + 2 * ks + kq) ^ sw) * 8];   \
    _Pragma("unroll")                                                     \
    for (int tn = 0; tn < 4; ++tn) {                                      \
      half8 bhi = *(const half8*)&BsG[BI][32 * tn + rl][((2 * ks + kq) ^ sw) * 8];    \
      half8 blo = *(const half8*)&BsG[BI][32 * tn + rl][((4 + 2 * ks + kq) ^ sw) * 8];\
      hh[tn] = MFMA32(ahi, bhi, hh[tn]);                                  \
      mx[tn] = MFMA32(ahi, blo, mx[tn]);                                  \
      mx[tn] = MFMA32(alo, bhi, mx[tn]);                                  \
    }                                                                     \
  }

    G_LOADREGS(0)
    G_WRITE(0)
    G_LOADREGS(32)
    BAR_LG()

    #pragma unroll 1
    for (int k0 = 0; k0 < Dd; k0 += 64) {
      G_KT(0)
      G_WRITE(1)
      if (k0 + 64 < Dd) { G_LOADREGS(k0 + 64) }
      BAR_LG()
      G_KT(1)
      if (k0 + 64 < Dd) { G_WRITE(0) }
      if (k0 + 96 < Dd) { G_LOADREGS(k0 + 96) }
      BAR_LG()
    }
#undef G_LOADREGS
#undef G_WRITE
#undef G_KT

    const float bb0 = BV[n0 + rl],      bb1 = BV[n0 + 32 + rl];
    const float bb2 = BV[n0 + 64 + rl], bb3 = BV[n0 + 96 + rl];
    #pragma unroll
    for (int j = 0; j < 16; ++j) {
      const int rtj = (j & 3) + 8 * (j >> 2) + 4 * kq;
      float* orow = &VOUT[(size_t)(m0 + 32 * w + rtj) * Dd + n0];
      orow[rl]      = hh[0][j] + mx[0][j] * (1.f / 2048.f) + bb0;
      orow[32 + rl] = hh[1][j] + mx[1][j] * (1.f / 2048.f) + bb1;
      orow[64 + rl] = hh[2][j] + mx[2][j] * (1.f / 2048.f) + bb2;
      orow[96 + rl] = hh[3][j] + mx[3][j] * (1.f / 2048.f) + bb3;
    }
  }
}

// ---------------------------------------------------------------------------
// Kernel 5: GEMM OUT = att@Wo + bo (R8 structure, frozen).
// ---------------------------------------------------------------------------
__global__ __launch_bounds__(256, 2) void gemm_kernel(
    const half_t* __restrict__ AHI, const half_t* __restrict__ ALO,
    const half_t* __restrict__ WHI,
    const float* __restrict__ BIAS, float* __restrict__ OUT)
{
  __shared__ __align__(16) half_t As[2][128][64];
  __shared__ __align__(16) half_t Bs[2][128][64];
  const int tid = threadIdx.x;
  const int m0 = blockIdx.x * 128, n0 = blockIdx.y * 128;

  f32x16 hh[4], mx[4];
  #pragma unroll
  for (int i = 0; i < 4; ++i) { hh[i] = (f32x16)(0.f); mx[i] = (f32x16)(0.f); }

  const int lane = tid & 63, w = tid >> 6;
  const int rl = lane & 31, kq = lane >> 5;
  const int sw = rl & 7;

  const int r = tid & 127, isB = tid >> 7;
  const int swr = r & 7;
  const half_t* srcHi = isB ? &WHI[(size_t)(n0 + r) * Dd]
                            : &AHI[(size_t)(m0 + r) * Dd];
  const half_t* srcLo = isB ? &WHI[1048576 + (size_t)(n0 + r) * Dd]
                            : &ALO[(size_t)(m0 + r) * Dd];
  half_t* dstRow = isB ? &Bs[0][r][0] : &As[0][r][0];
  const int pc0 = (0 ^ swr) * 8, pc1 = (1 ^ swr) * 8;
  const int pc2 = (2 ^ swr) * 8, pc3 = (3 ^ swr) * 8;
  const int pc4 = (4 ^ swr) * 8, pc5 = (5 ^ swr) * 8;
  const int pc6 = (6 ^ swr) * 8, pc7 = (7 ^ swr) * 8;

  half8 rg0, rg1, rg2, rg3, rg4, rg5, rg6, rg7;

#define G_LOADREGS(K)                                                          \
  rg0 = *(const half8*)&srcHi[(K)];      rg1 = *(const half8*)&srcHi[(K) + 8]; \
  rg2 = *(const half8*)&srcHi[(K) + 16]; rg3 = *(const half8*)&srcHi[(K) + 24];\
  rg4 = *(const half8*)&srcLo[(K)];      rg5 = *(const half8*)&srcLo[(K) + 8]; \
  rg6 = *(const half8*)&srcLo[(K) + 16]; rg7 = *(const half8*)&srcLo[(K) + 24];

#define G_WRITE(BI) {                                                     \
  half_t* d_ = dstRow + (BI) * 8192;                                      \
  *(half8*)&d_[pc0] = rg0; *(half8*)&d_[pc1] = rg1;                       \
  *(half8*)&d_[pc2] = rg2; *(half8*)&d_[pc3] = rg3;                       \
  *(half8*)&d_[pc4] = rg4; *(half8*)&d_[pc5] = rg5;                       \
  *(half8*)&d_[pc6] = rg6; *(half8*)&d_[pc7] = rg7; }

#define G_KT(BI)                                                          \
  _Pragma("unroll")                                                       \
  for (int ks = 0; ks < 2; ++ks) {                                        \
    half8 ahi = *(const half8*)&As[BI][32 * w + rl][((2 * ks + kq) ^ sw) * 8];       \
    half8 alo = *(const half8*)&As[BI][32 * w + rl][((4 + 2 * ks + kq) ^ sw) * 8];   \
    _Pragma("unroll")                                                     \
    for (int tn = 0; tn < 4; ++tn) {                                      \
      half8 bhi = *(const half8*)&Bs[BI][32 * tn + rl][((2 * ks + kq) ^ sw) * 8];    \
      half8 blo = *(const half8*)&Bs[BI][32 * tn + rl][((4 + 2 * ks + kq) ^ sw) * 8];\
      hh[tn] = MFMA32(ahi, bhi, hh[tn]);                                  \
      mx[tn] = MFMA32(ahi, blo, mx[tn]);                                  \
      mx[tn] = MFMA32(alo, bhi, mx[tn]);                                  \
    }                                                                     \
  }

  G_LOADREGS(0)
  G_WRITE(0)
  G_LOADREGS(32)
  BAR_LG()

  #pragma unroll 1
  for (int k0 = 0; k0 < Dd; k0 += 64) {
    G_KT(0)
    G_WRITE(1)
    if (k0 + 64 < Dd) { G_LOADREGS(k0 + 64) }
    BAR_LG()
    G_KT(1)
    if (k0 + 64 < Dd) { G_WRITE(0) }
    if (k0 + 96 < Dd) { G_LOADREGS(k0 + 96) }
    BAR_LG()
  }
#undef G_LOADREGS
#undef G_WRITE
#undef G_KT

  const float bb0 = BIAS[n0 + rl],      bb1 = BIAS[n0 + 32 + rl];
  const float bb2 = BIAS[n0 + 64 + rl], bb3 = BIAS[n0 + 96 + rl];
  #pragma unroll
  for (int j = 0; j < 16; ++j) {
    const int rtj = (j & 3) + 8 * (j >> 2) + 4 * kq;
    float* orow = &OUT[(size_t)(m0 + 32 * w + rtj) * Dd + n0];
    orow[rl]      = hh[0][j] + mx[0][j] * (1.f / 2048.f) + bb0;
    orow[32 + rl] = hh[1][j] + mx[1][j] * (1.f / 2048.f) + bb1;
    orow[64 + rl] = hh[2][j] + mx[2][j] * (1.f / 2048.f) + bb2;
    orow[96 + rl] = hh[3][j] + mx[3][j] * (1.f / 2048.f) + bb3;
  }
}

// ---------------------------------------------------------------------------
// Kernel 2: G_c = K_c^T V_c on MFMA32. LDS: KT fp16 [64][64] (KT[i][s] =
// K[s][i]); VThi/VTlo split (VT[d][s] = V[s][d]). Chunk swizzle c^(row&7).
// 4 waves = 2x2 (wm: i-tile, wn: d-tile); 8 MFMA/wave.
// ---------------------------------------------------------------------------
__global__ __launch_bounds__(256) void chunk_kv_kernel(
    const half_t* __restrict__ KNH, const float* __restrict__ V,
    float* __restrict__ G)
{
  __shared__ __align__(16) half_t KT[4096];
  __shared__ __align__(16) half_t VThi[4096];
  __shared__ __align__(16) half_t VTlo[4096];
  const int tid = threadIdx.x;
  const int c = blockIdx.x, h = blockIdx.y, b = blockIdx.z;
  const int s0 = c * 64;
  {
    const int s = tid >> 2, q = tid & 3;
    const half_t* krow = &KNH[(size_t)(b * Tt + s0 + s) * Dd + h * 64 + q * 16];
    half8 ka = *(const half8*)&krow[0];
    half8 kb = *(const half8*)&krow[8];
    const float* vrow = &V[(size_t)(b * Tt + s0 + s) * Dd + h * 64 + q * 16];
    float4 va = *(const float4*)&vrow[0];
    float4 vb = *(const float4*)&vrow[4];
    float4 vc = *(const float4*)&vrow[8];
    float4 vd = *(const float4*)&vrow[12];
    const float vv[16] = {va.x,va.y,va.z,va.w, vb.x,vb.y,vb.z,vb.w,
                          vc.x,vc.y,vc.z,vc.w, vd.x,vd.y,vd.z,vd.w};
    const int scq = s >> 3, se = s & 7;
    #pragma unroll
    for (int i = 0; i < 16; ++i) {
      const int r = q * 16 + i;                       // dest row (i or d)
      const int addr = r * 64 + ((scq ^ (r & 7)) << 3) + se;
      KT[addr] = (i < 8) ? ka[i] : kb[i - 8];
      const float f = vv[i];
      half_t hx = (half_t)f;
      VThi[addr] = hx;
      VTlo[addr] = (half_t)((f - (float)hx) * 2048.f);
    }
  }
  __syncthreads();

  const int lane = tid & 63, wv = tid >> 6;
  const int rl = lane & 31, kq = lane >> 5;
  const int sw = rl & 7;
  const int wm = wv >> 1, wn = wv & 1;
  f32x16 hh = (f32x16)(0.f), mx = (f32x16)(0.f);
  const int ra = (32 * wm + rl) * 64;
  const int rb = (32 * wn + rl) * 64;
  #pragma unroll
  for (int kt = 0; kt < 4; ++kt) {
    const int ch = ((2 * kt + kq) ^ sw) * 8;
    half8 a  = *(const half8*)&KT[ra + ch];
    half8 bh = *(const half8*)&VThi[rb + ch];
    half8 bl = *(const half8*)&VTlo[rb + ch];
    hh = MFMA32(a, bh, hh);
    mx = MFMA32(a, bl, mx);
  }
  float* Gp = G + (((size_t)(b * Hh + h) * NC + c) << 12);
  #pragma unroll
  for (int j = 0; j < 16; ++j) {
    const int rtj = (j & 3) + 8 * (j >> 2) + 4 * kq;
    Gp[(32 * wm + rtj) * 64 + 32 * wn + rl] = hh[j] + mx[j] * (1.f / 2048.f);
  }
}

// ---------------------------------------------------------------------------
// Kernel 3: in-place exclusive prefix over NC chunk matrices per (b,h).
// ---------------------------------------------------------------------------
__global__ __launch_bounds__(256) void prefix_kernel(float* __restrict__ G)
{
  const int seg = blockIdx.x, h = blockIdx.y, b = blockIdx.z;
  float* base = G + (((size_t)(b * Hh + h) * NC) << 12) + seg * 256 + threadIdx.x;
  float acc = 0.f;
  #pragma unroll 4
  for (int c = 0; c < NC; ++c) {
    float* p = base + ((size_t)c << 12);
    const float g = *p;
    *p = acc;
    acc += g;
  }
}

// ---------------------------------------------------------------------------
// Kernel 4: O_c = (Q_c M_c + tril(Q_c K_c^T) V_c) * scale/sqrt(t+1), MFMA32.
// Q/K frags direct from global (row-major fp16). S = QK^T (4 fp16 MFMA),
// mask per C-layout, split -> Shi/Slo LDS; one barrier; O = Q@MT + S@VT
// (MT, VT transposed+split at stage). Out split to ATTHI/ATTLO.
// 4 waves = 2x2 (wm: t-tile, wn: d/s-tile). LDS 48KB.
// ---------------------------------------------------------------------------
__global__ __launch_bounds__(256) void attn_chunk_kernel(
    const half_t* __restrict__ QNH, const half_t* __restrict__ KNH,
    const float* __restrict__ V, const float* __restrict__ M,
    const float* __restrict__ SCALE,
    half_t* __restrict__ ATTHI, half_t* __restrict__ ATTLO)
{
  __shared__ __align__(16) half_t MThi[4096];
  __shared__ __align__(16) half_t MTlo[4096];
  __shared__ __align__(16) half_t VThi[4096];
  __shared__ __align__(16) half_t VTlo[4096];
  __shared__ __align__(16) half_t Shi[4096];
  __shared__ __align__(16) half_t Slo[4096];
  const int tid = threadIdx.x;
  const int c = blockIdx.x, h = blockIdx.y, b = blockIdx.z;
  const int t0 = c * 64, col0 = h * 64;

  // stage M^T and V^T (transpose + split). src row s (=w for M, =s for V).
  {
    const int s = tid >> 2, q = tid & 3;
    const float* mrow = &M[(((size_t)(b * Hh + h) * NC + c) << 12) + s * 64 + q * 16];
    const float* vrow = &V[(size_t)(b * Tt + t0 + s) * Dd + col0 + q * 16];
    float4 ma = *(const float4*)&mrow[0];
    float4 mb = *(const float4*)&mrow[4];
    float4 mc = *(const float4*)&mrow[8];
    float4 md = *(const float4*)&mrow[12];
    float4 va = *(const float4*)&vrow[0];
    float4 vb = *(const float4*)&vrow[4];
    float4 vc = *(const float4*)&vrow[8];
    float4 vd = *(const float4*)&vrow[12];
    const float mv[16] = {ma.x,ma.y,ma.z,ma.w, mb.x,mb.y,mb.z,mb.w,
                          mc.x,mc.y,mc.z,mc.w, md.x,md.y,md.z,md.w};
    const float vV[16] = {va.x,va.y,va.z,va.w, vb.x,vb.y,vb.z,vb.w,
                          vc.x,vc.y,vc.z,vc.w, vd.x,vd.y,vd.z,vd.w};
    const int scq = s >> 3, se = s & 7;
    #pragma unroll
    for (int i = 0; i < 16; ++i) {
      const int r = q * 16 + i;                       // dest row (d index)
      const int addr = r * 64 + ((scq ^ (r & 7)) << 3) + se;
      float fm = mv[i];
      half_t mh = (half_t)fm;
      MThi[addr] = mh;
      MTlo[addr] = (half_t)((fm - (float)mh) * 2048.f);
      float fv = vV[i];
      half_t vh = (half_t)fv;
      VThi[addr] = vh;
      VTlo[addr] = (half_t)((fv - (float)vh) * 2048.f);
    }
  }

  const int lane = tid & 63, wv = tid >> 6;
  const int rl = lane & 31, kq = lane >> 5;
  const int sw = rl & 7;
  const int wm = wv >> 1, wn = wv & 1;

  // Q (A, rows t) and K (B, rows s) fragments from global, k = NW dim.
  const half_t* qp = &QNH[(size_t)(b * Tt + t0 + 32 * wm + rl) * Dd + col0 + kq * 8];
  const half_t* kp = &KNH[(size_t)(b * Tt + t0 + 32 * wn + rl) * Dd + col0 + kq * 8];
  half8 qf0 = *(const half8*)&qp[0],  qf1 = *(const half8*)&qp[16];
  half8 qf2 = *(const half8*)&qp[32], qf3 = *(const half8*)&qp[48];
  half8 kf0 = *(const half8*)&kp[0],  kf1 = *(const half8*)&kp[16];
  half8 kf2 = *(const half8*)&kp[32], kf3 = *(const half8*)&kp[48];

  f32x16 S = (f32x16)(0.f);
  S = MFMA32(qf0, kf0, S);
  S = MFMA32(qf1, kf1, S);
  S = MFMA32(qf2, kf2, S);
  S = MFMA32(qf3, kf3, S);

  // mask (s <= t) + split to LDS
  {
    const int sl = 32 * wn + rl;                      // s index (C col)
    const int scq = sl >> 3, se = sl & 7;
    #pragma unroll
    for (int j = 0; j < 16; ++j) {
      const int rtj = (j & 3) + 8 * (j >> 2) + 4 * kq;
      const int tl = 32 * wm + rtj;                   // t index (C row)
      const float v = (sl <= tl) ? S[j] : 0.f;
      half_t hx = (half_t)v;
      const int addr = tl * 64 + ((scq ^ (tl & 7)) << 3) + se;
      Shi[addr] = hx;
      Slo[addr] = (half_t)((v - (float)hx) * 2048.f);
    }
  }
  __syncthreads();

  f32x16 hhO = (f32x16)(0.f), mxO = (f32x16)(0.f);
  const int raS = (32 * wm + rl) * 64;                // S rows (t)
  const int rbD = (32 * wn + rl) * 64;                // MT/VT rows (d)
  #pragma unroll
  for (int kt = 0; kt < 4; ++kt) {
    const int ch = ((2 * kt + kq) ^ sw) * 8;
    half8 qf = (kt == 0) ? qf0 : (kt == 1) ? qf1 : (kt == 2) ? qf2 : qf3;
    half8 bmh = *(const half8*)&MThi[rbD + ch];
    half8 bml = *(const half8*)&MTlo[rbD + ch];
    hhO = MFMA32(qf, bmh, hhO);
    mxO = MFMA32(qf, bml, mxO);
    half8 sh  = *(const half8*)&Shi[raS + ch];
    half8 sl8 = *(const half8*)&Slo[raS + ch];
    half8 bvh = *(const half8*)&VThi[rbD + ch];
    half8 bvl = *(const half8*)&VTlo[rbD + ch];
    hhO = MFMA32(sh, bvh, hhO);
    mxO = MFMA32(sh, bvl, mxO);
    mxO = MFMA32(sl8, bvh, mxO);
  }

  const float sch = SCALE[h];
  #pragma unroll
  for (int j = 0; j < 16; ++j) {
    const int rtj = (j & 3) + 8 * (j >> 2) + 4 * kq;
    const int t = t0 + 32 * wm + rtj;
    const float fac = sch / sqrtf((float)(t + 1));
    const float v = (hhO[j] + mxO[j] * (1.f / 2048.f)) * fac;
    half_t hx = (half_t)v;
    const size_t oaddr = (size_t)(b * Tt + t) * Dd + col0 + 32 * wn + rl;
    ATTHI[oaddr] = hx;
    ATTLO[oaddr] = (half_t)((v - (float)hx) * 2048.f);
  }
}

// ---------------------------------------------------------------------------
extern "C" void kernel_launch(void* const* d_in, const int* in_sizes, int n_in,
                              void* d_out, int out_size, void* d_ws, size_t ws_size,
                              hipStream_t stream) {
  const float* x   = (const float*)d_in[0];
  const float* Wqf = (const float*)d_in[1];
  const float* bqf = (const float*)d_in[2];
  const float* Wkf = (const float*)d_in[3];
  const float* bkf = (const float*)d_in[4];
  const float* Wqp = (const float*)d_in[5];
  const float* bqp = (const float*)d_in[6];
  const float* Wkp = (const float*)d_in[7];
  const float* bkp = (const float*)d_in[8];
  const float* Wv  = (const float*)d_in[9];
  const float* bv  = (const float*)d_in[10];
  const float* Wo  = (const float*)d_in[11];
  const float* bo  = (const float*)d_in[12];
  const float* scale = (const float*)d_in[13];

  // ws layout (56 MB): Wsplit 24 MB | qnh 8 MB | knh 8 MB | G 16 MB
  half_t* WSP = (half_t*)d_ws;                 // 6 mats x (hi 1M + lo 1M) halves
  half_t* qnh = WSP + 12582912;                // 4,194,304 halves
  half_t* knh = qnh + 4194304;
  float*  G   = (float*)(knh + 4194304);
  half_t* xhi = (half_t*)G;                    // x halves alias G: dead before
  half_t* xlo = xhi + 4194304;                 // chunk_kv writes G
  float*  vbuf = (float*)d_out;                // v lives in d_out, consumed
                                               // before the final out-gemm

  // mat order in WSP: 0=qf 1=qp 2=kf 3=kp 4=v 5=o
  xwsplit_kernel<<<dim3(2048 + 1536), 256, 0, stream>>>(
      x, Wqf, Wqp, Wkf, Wkp, Wv, Wo, xhi, xlo, WSP);

  projv_kernel<<<dim3(1024 + 256), 256, 0, stream>>>(
      xhi, xlo, WSP, bqf, bqp, bkf, bkp, qnh, knh, bv, vbuf);

  chunk_kv_kernel<<<dim3(NC, Hh, Bb), 256, 0, stream>>>(knh, vbuf, G);
  prefix_kernel<<<dim3(16, Hh, Bb), 256, 0, stream>>>(G);
  attn_chunk_kernel<<<dim3(NC, Hh, Bb), 256, 0, stream>>>(
      qnh, knh, vbuf, G, scale, qnh /*atthi*/, knh /*attlo*/);

  gemm_kernel<<<dim3((Bb * Tt) / 128, Dd / 128), 256, 0, stream>>>(
      qnh, knh, WSP + (size_t)5 * 2097152, bo, (float*)d_out);
}